// Round 4
// baseline (387.278 us; speedup 1.0000x reference)
//
#include <hip/hip_runtime.h>
#include <hip/hip_bf16.h>
#include <stdint.h>

// CrossAttention (B=4, N=M=4096, C=512), fp32 in/out, bf16 MFMA internally.
// Round 9: fix pv_gemm race (round 8 lacked explicit lgkmcnt(0) before the
// WAR barrier -> rule #18 MFMA/wait sinking let restage overwrite LDS under
// in-flight ds_reads). pv body now mirrors the VERIFIED gemm256_exp phase:
// {stage; ds_read} -> barrier -> lgkmcnt(0)+sched_barrier(0) -> MFMA ->
// vmcnt(counted) -> barrier -> mem-fence. Also deepened to 4 LDS buffers
// (lead ~2.7 bodies to cover ~900cy HBM latency on the cold Sb stream).
//   Q    = rgb @ WqT^T (+bq)          [16384 x 512]        gemm32
//   K    = dep @ WkT^T (+bk)          [16384 x 512]        gemm32
//   Vt   = WvT @ dep^T (+bv row)      per batch [512x4096] gemm32
//   expS = exp(Q K^T / sqrt(C))       per batch [4096^2]   gemm256_exp
//   O    = (expS @ Vt^T) / rowsum     per batch [4096x512] pv_gemm (FIXED)

typedef unsigned short u16;
typedef __attribute__((ext_vector_type(8))) short bf16x8;
typedef __attribute__((ext_vector_type(16))) float f32x16;
typedef __attribute__((ext_vector_type(4))) unsigned short u16x4;

#define GLD_LDS16(g, l)                                                        \
  __builtin_amdgcn_global_load_lds(                                            \
      (const __attribute__((address_space(1))) unsigned int*)(g),              \
      (__attribute__((address_space(3))) unsigned int*)(l), 16, 0, 0)

__device__ __forceinline__ u16 f2bf(float f) {  // RNE f32 -> bf16
  unsigned x = __float_as_uint(f);
  return (u16)((x + 0x7fffu + ((x >> 16) & 1u)) >> 16);
}
__device__ __forceinline__ float bf2f(short s) {
  return __uint_as_float((unsigned)(unsigned short)s << 16);
}

// ---------------------------------------------------------------------------
// GEMM: C[M,N] = A[M,K]*B[N,K]^T, bf16 in, fp32 acc, 32x32x16 MFMA.
// 256 thr / 4 waves (2x2), TM x TN tile, BK=32, double-buffered LDS, one
// barrier per iter. XOR bank swizzle on 16-B k-chunks (R3: 0 conflicts).
// OUT_MODE: 0 = bf16, 1 = fp32. BIAS_MODE: 0 none, 1 bias[col], 2 bias[row].
// ---------------------------------------------------------------------------
template <int TM, int TN, int BIAS_MODE, int OUT_MODE, int MINW>
__global__ __launch_bounds__(256, MINW) void gemm32(
    const u16* __restrict__ A, const u16* __restrict__ Bm,
    const float* __restrict__ bias, void* __restrict__ Cv, int M, int N, int K,
    long long sAb, long long sBb, long long sCb, float scale) {
  constexpr int WROWS = TM / 2;
  constexpr int WCOLS = TN / 2;
  constexpr int MSUB = WROWS / 32;
  constexpr int NSUB = WCOLS / 32;
  constexpr int CA = TM / 64;  // A 16-row chunks per wave
  constexpr int CB = TN / 64;  // B 16-row chunks per wave

  const int bz = blockIdx.z;
  A += (size_t)bz * sAb;
  Bm += (size_t)bz * sBb;

  const int bm = blockIdx.y * TM;
  const int bn = blockIdx.x * TN;

  __shared__ u16 As[2][TM * 32];
  __shared__ u16 Bs[2][TN * 32];

  const int tid = threadIdx.x;
  const int wave = tid >> 6;
  const int lane = tid & 63;
  const int ln31 = lane & 31;
  const int half = lane >> 5;
  const int wr = wave >> 1;
  const int wc = wave & 1;

  const int rowA = lane >> 2;
  const int swz = ((lane & 3) ^ ((rowA + (rowA >> 2)) & 3)) * 8;
  const int gl = (ln31 + (ln31 >> 2)) & 3;

  f32x16 acc[MSUB][NSUB] = {};

  auto stage = [&](int buf, int k0) {
#pragma unroll
    for (int r = 0; r < CA; ++r) {
      const int ch = wave * CA + r;
      GLD_LDS16(A + (size_t)(bm + ch * 16 + rowA) * K + k0 + swz,
                As[buf] + ch * 16 * 32);
    }
#pragma unroll
    for (int r = 0; r < CB; ++r) {
      const int ch = wave * CB + r;
      GLD_LDS16(Bm + (size_t)(bn + ch * 16 + rowA) * K + k0 + swz,
                Bs[buf] + ch * 16 * 32);
    }
  };

  const int niter = K >> 5;
  stage(0, 0);
  for (int it = 0; it < niter; ++it) {
    __syncthreads();  // publishes buf it&1 (vmcnt drained here)
    if (it + 1 < niter) stage((it + 1) & 1, (it + 1) * 32);
    const int buf = it & 1;
#pragma unroll
    for (int kc = 0; kc < 2; ++kc) {
      const int p = ((kc * 2 + half) ^ gl) * 8;
      bf16x8 af[MSUB], bfv[NSUB];
#pragma unroll
      for (int mt = 0; mt < MSUB; ++mt)
        af[mt] =
            *(const bf16x8*)&As[buf][(wr * WROWS + mt * 32 + ln31) * 32 + p];
#pragma unroll
      for (int nt = 0; nt < NSUB; ++nt)
        bfv[nt] =
            *(const bf16x8*)&Bs[buf][(wc * WCOLS + nt * 32 + ln31) * 32 + p];
#pragma unroll
      for (int mt = 0; mt < MSUB; ++mt)
#pragma unroll
        for (int nt = 0; nt < NSUB; ++nt)
          acc[mt][nt] = __builtin_amdgcn_mfma_f32_32x32x16_bf16(
              af[mt], bfv[nt], acc[mt][nt], 0, 0, 0);
    }
  }

  // Epilogue. 32x32 C/D layout: col = lane&31, row = (r&3)+8*(r>>2)+4*half.
  const int crow0 = bm + wr * WROWS + 4 * half;
  const int ccol0 = bn + wc * WCOLS + ln31;
#pragma unroll
  for (int mt = 0; mt < MSUB; ++mt) {
#pragma unroll
    for (int nt = 0; nt < NSUB; ++nt) {
      const int col = ccol0 + nt * 32;
#pragma unroll
      for (int r = 0; r < 16; ++r) {
        const int row = crow0 + mt * 32 + (r & 3) + 8 * (r >> 2);
        float v = acc[mt][nt][r];
        if constexpr (BIAS_MODE == 1) v += bias[col];
        if constexpr (BIAS_MODE == 2) v += bias[row];
        const size_t idx = (size_t)bz * (size_t)sCb + (size_t)row * N + col;
        if constexpr (OUT_MODE == 0)
          ((u16*)Cv)[idx] = f2bf(v);
        else if constexpr (OUT_MODE == 1)
          ((float*)Cv)[idx] = v;
        else
          ((u16*)Cv)[idx] = f2bf(__expf(v * scale));
      }
    }
  }
}

// ---------------------------------------------------------------------------
// gemm256_exp: S[4096,4096] = exp(scale * Q[4096,512] K[4096,512]^T) in bf16.
// 256x256 tile, BK=64, 512 thr / 8 waves (2M x 4N), per-wave 128x64 output.
// 4 quadrant-phases per K-tile; counted vmcnt 4/5/6/3 (never 0 mid-loop).
// Verified passing (incl. replay tripwire) in Round 7/8. Unchanged.
// ---------------------------------------------------------------------------
#define XA_STGA(buf, j, k0)                                                    \
  GLD_LDS16(Ag + (size_t)((j) * 32 + (wv & 3) * 8 + (wv >> 2) * 128 + rlane) * \
                    512 +                                                      \
                (k0) + swz8,                                                   \
            &As[buf][((j) * 32 + (wv & 3) * 8 + (wv >> 2) * 128) * 64])
#define XA_STGB(buf, j, k0)                                                    \
  GLD_LDS16(Bg + (size_t)((j) * 64 + wv * 8 + rlane) * 512 + (k0) + swz8,      \
            &Bs[buf][((j) * 64 + wv * 8) * 64])

#define XA_PHASE(F, NV, PFS)                                                   \
  {                                                                            \
    bf16x8 af[4];                                                              \
    {                                                                          \
      const int arow = (wm * 128 + (F) * 32 + ln31) * 64;                      \
      _Pragma("unroll") for (int k = 0; k < 4; ++k) af[k] =                    \
          *(const bf16x8*)&As[p][arow + (((2 * k + half) ^ s7) << 3)];         \
    }                                                                          \
    if ((F) == 0) {                                                            \
      _Pragma("unroll") for (int n = 0; n < 2; ++n) {                          \
        const int brow = (wn * 64 + n * 32 + ln31) * 64;                       \
        _Pragma("unroll") for (int k = 0; k < 4; ++k) bfr[n][k] =              \
            *(const bf16x8*)&Bs[p][brow + (((2 * k + half) ^ s7) << 3)];       \
      }                                                                        \
    }                                                                          \
    PFS;                                                                       \
    __builtin_amdgcn_s_barrier();                                              \
    asm volatile("s_waitcnt lgkmcnt(0)" ::: "memory");                         \
    __builtin_amdgcn_sched_barrier(0);                                         \
    __builtin_amdgcn_s_setprio(1);                                             \
    _Pragma("unroll") for (int k = 0; k < 4; ++k) {                            \
      acc[F][0] = __builtin_amdgcn_mfma_f32_32x32x16_bf16(af[k], bfr[0][k],    \
                                                          acc[F][0], 0, 0, 0); \
      acc[F][1] = __builtin_amdgcn_mfma_f32_32x32x16_bf16(af[k], bfr[1][k],    \
                                                          acc[F][1], 0, 0, 0); \
    }                                                                          \
    __builtin_amdgcn_s_setprio(0);                                             \
    asm volatile("s_waitcnt vmcnt(" NV ")" ::: "memory");                      \
    __builtin_amdgcn_s_barrier();                                              \
    asm volatile("" ::: "memory");                                             \
  }

__global__ __launch_bounds__(512, 2) void gemm256_exp(
    const u16* __restrict__ Qm, const u16* __restrict__ Km,
    u16* __restrict__ Sout, long long sAb, long long sSb, float scale) {
  const int bz = blockIdx.z;
  const int bm = blockIdx.y * 256;
  const int bn = blockIdx.x * 256;
  const u16* Ag = Qm + (size_t)bz * (size_t)sAb + (size_t)bm * 512;
  const u16* Bg = Km + (size_t)bz * (size_t)sAb + (size_t)bn * 512;

  __shared__ u16 As[2][256 * 64];  // 64 KB
  __shared__ u16 Bs[2][256 * 64];  // 64 KB

  const int tid = threadIdx.x;
  const int wv = tid >> 6;    // wave 0..7
  const int lane = tid & 63;
  const int ln31 = lane & 31;
  const int half = lane >> 5;
  const int wm = wv >> 2;     // 0..1: 128-row half
  const int wn = wv & 3;      // 0..3: 64-col group
  const int rlane = lane >> 3;                 // staged row within 8-row chunk
  const int swz8 = ((lane & 7) ^ rlane) << 3;  // pre-swizzled global k-offset
  const int s7 = ln31 & 7;                     // ds_read swizzle key

  f32x16 acc[4][2] = {};
  bf16x8 bfr[2][4];

  // prologue: stage tile 0 into buf 0 (issue order B0..B3, A0..A3)
#pragma unroll
  for (int j = 0; j < 4; ++j) XA_STGB(0, j, 0);
#pragma unroll
  for (int j = 0; j < 4; ++j) XA_STGA(0, j, 0);
  asm volatile("s_waitcnt vmcnt(3)" ::: "memory");  // B0-3 + A0 landed
  __builtin_amdgcn_s_barrier();
  asm volatile("" ::: "memory");

  for (int t = 0; t < 7; ++t) {  // K = 512 -> 8 tiles of 64
    const int p = t & 1;
    const int q = p ^ 1;
    const int kn = (t + 1) << 6;
    XA_PHASE(0, "4", { XA_STGB(q, 0, kn); XA_STGB(q, 1, kn); });
    XA_PHASE(1, "5", { XA_STGB(q, 2, kn); XA_STGB(q, 3, kn); });
    XA_PHASE(2, "6", { XA_STGA(q, 0, kn); XA_STGA(q, 1, kn); });
    XA_PHASE(3, "3", { XA_STGA(q, 2, kn); XA_STGA(q, 3, kn); });
  }
  {  // last tile: no prefetch, drain progressively
    const int p = 1;
    XA_PHASE(0, "2", {});
    XA_PHASE(1, "1", {});
    XA_PHASE(2, "0", {});
    XA_PHASE(3, "0", {});
  }

  // epilogue: exp + bf16 store. 32x32 layout: col=lane&31, row=(r&3)+8*(r>>2)+4*half.
  const size_t ob = (size_t)bz * (size_t)sSb;
  const int c0 = bn + wn * 64 + ln31;
  const int r0 = bm + wm * 128 + 4 * half;
#pragma unroll
  for (int m = 0; m < 4; ++m) {
#pragma unroll
    for (int n = 0; n < 2; ++n) {
      const int col = c0 + n * 32;
#pragma unroll
      for (int r = 0; r < 16; ++r) {
        const int row = r0 + m * 32 + (r & 3) + 8 * (r >> 2);
        Sout[ob + (size_t)row * 4096 + col] = f2bf(__expf(acc[m][n][r] * scale));
      }
    }
  }
}

// ---------------------------------------------------------------------------
// PV: O[64 q x 256 d] = (expS_slab @ Vt^T) / den. 256 thr / 4 waves, each
// wave owns a 64-d group; all waves share the same 64 q rows.
// Round 9 body (gemm256_exp-proven ordering):
//   {stage(t+3); ds_read tile t} -> s_barrier -> lgkmcnt(0)+sched_barrier(0)
//   -> setprio(1) 20 MFMA setprio(0) -> vmcnt(counted) -> s_barrier -> fence.
// WAR: reads of buf[(t-1)&3] complete at body t-1's EXPLICIT lgkmcnt(0),
//   which precedes its end barrier; stage(t+3) (same buffer) issues after.
// RAW: end-of-body-t vmcnt(10) leaves only stages t+2,t+3 (2x5 loads) in
//   flight -> tile t+1 resident before the barrier releases body t+1 reads.
// 4 buffers (80 KB, exactly 2 blocks/CU @ grid 512): stage lead ~2.7 bodies
// to cover HBM latency on the cold Sb stream. Tail vmcnt 10/5/0.
// den via ones-MFMA: dacc[mt] = mfma(af, ones, dacc) — rowsum in the same
// C/D layout as acc (verified numerics: absmax 0.00195 pre-timing, R8).
// ---------------------------------------------------------------------------
#define PV_BODY(IT, NV, DO_STAGE, DO_TAIL)                                     \
  {                                                                            \
    const int buf = (IT) & 3;                                                  \
    if (DO_STAGE) stage(((IT) + 3) & 3, ((IT) + 3) * 32);                      \
    bf16x8 af[2][2], bfv[2][2];                                                \
    _Pragma("unroll") for (int kc = 0; kc < 2; ++kc) {                         \
      const int p = ((kc * 2 + half) ^ gl) * 8;                                \
      _Pragma("unroll") for (int mt = 0; mt < 2; ++mt)                         \
        af[kc][mt] = *(const bf16x8*)&As[buf][(mt * 32 + ln31) * 32 + p];      \
      _Pragma("unroll") for (int nt = 0; nt < 2; ++nt)                         \
        bfv[kc][nt] =                                                          \
            *(const bf16x8*)&Bs[buf][(wave * 64 + nt * 32 + ln31) * 32 + p];   \
    }                                                                          \
    __builtin_amdgcn_s_barrier();                                              \
    asm volatile("s_waitcnt lgkmcnt(0)" ::: "memory");                         \
    __builtin_amdgcn_sched_barrier(0);                                         \
    __builtin_amdgcn_s_setprio(1);                                             \
    _Pragma("unroll") for (int kc = 0; kc < 2; ++kc) {                         \
      _Pragma("unroll") for (int mt = 0; mt < 2; ++mt) {                       \
        dacc[mt] = __builtin_amdgcn_mfma_f32_32x32x16_bf16(                    \
            af[kc][mt], onesv, dacc[mt], 0, 0, 0);                             \
        _Pragma("unroll") for (int nt = 0; nt < 2; ++nt)                       \
          acc[mt][nt] = __builtin_amdgcn_mfma_f32_32x32x16_bf16(               \
              af[kc][mt], bfv[kc][nt], acc[mt][nt], 0, 0, 0);                  \
      }                                                                        \
    }                                                                          \
    __builtin_amdgcn_s_setprio(0);                                             \
    if (DO_TAIL) {                                                             \
      asm volatile("s_waitcnt vmcnt(" NV ")" ::: "memory");                    \
      __builtin_amdgcn_s_barrier();                                            \
      asm volatile("" ::: "memory");                                           \
    }                                                                          \
  }

__global__ __launch_bounds__(256, 2) void pv_gemm(
    const u16* __restrict__ P, const u16* __restrict__ Vt,
    float* __restrict__ O) {
  const int bz = blockIdx.z;
  const u16* A = P + (size_t)bz * (4096ull * 4096ull);
  const u16* B = Vt + (size_t)bz * (512ull * 4096ull);
  float* Ob = O + (size_t)bz * (4096ull * 512ull);

  const int bm = blockIdx.y * 64;   // q-row slab
  const int bn = blockIdx.x * 256;  // d half

  __shared__ u16 As[4][64 * 32];   // 4 x 4 KB
  __shared__ u16 Bs[4][256 * 32];  // 4 x 16 KB  (total 80 KB -> 2 blocks/CU)

  const int tid = threadIdx.x;
  const int wave = tid >> 6;  // d-group 0..3
  const int lane = tid & 63;
  const int ln31 = lane & 31;
  const int half = lane >> 5;

  const int rowA = lane >> 2;
  const int swz = ((lane & 3) ^ ((rowA + (rowA >> 2)) & 3)) * 8;
  const int gl = (ln31 + (ln31 >> 2)) & 3;

  f32x16 acc[2][2] = {};
  f32x16 dacc[2] = {};
  bf16x8 onesv;
#pragma unroll
  for (int j = 0; j < 8; ++j) onesv[j] = (short)0x3F80;  // bf16 1.0

  auto stage = [&](int buf, int k0) {
    // A: 4 chunks of 16 rows, one per wave (HBM-cold Sb — issue first).
    GLD_LDS16(A + (size_t)(bm + wave * 16 + rowA) * 4096 + k0 + swz,
              As[buf] + wave * 16 * 32);
    // B: 16 chunks, 4 per wave (L2-resident Vt).
#pragma unroll
    for (int r = 0; r < 4; ++r) {
      const int ch = wave * 4 + r;
      GLD_LDS16(B + (size_t)(bn + ch * 16 + rowA) * 4096 + k0 + swz,
                Bs[buf] + ch * 16 * 32);
    }
  };

  // prologue: stage tiles 0..2; wait tile 0 (15 issued, allow 10); publish.
  stage(0, 0);
  stage(1, 32);
  stage(2, 64);
  asm volatile("s_waitcnt vmcnt(10)" ::: "memory");
  __builtin_amdgcn_s_barrier();
  asm volatile("" ::: "memory");

  for (int it = 0; it < 125; ++it) PV_BODY(it, "10", true, true);
  PV_BODY(125, "5", false, true);
  PV_BODY(126, "0", false, true);
  PV_BODY(127, "0", false, false);  // last body: no tail barrier needed

  // Epilogue: rd = 1/dacc — same C/D row mapping as acc, zero cross-lane.
  const int crow0 = 4 * half;
  const int ccol0 = bn + wave * 64 + ln31;
#pragma unroll
  for (int mt = 0; mt < 2; ++mt) {
#pragma unroll
    for (int r = 0; r < 16; ++r) {
      const int rl = crow0 + mt * 32 + (r & 3) + 8 * (r >> 2);
      const float rd = 1.0f / dacc[mt][r];
#pragma unroll
      for (int nt = 0; nt < 2; ++nt)
        Ob[(size_t)(bm + rl) * 512 + ccol0 + nt * 32] = acc[mt][nt][r] * rd;
    }
  }
}

// ---------------------------------------------------------------------------
__global__ __launch_bounds__(256) void cvt_pair(const float* __restrict__ x,
                                                const float* __restrict__ y,
                                                u16* __restrict__ ox,
                                                u16* __restrict__ oy, int n4) {
  const int i = blockIdx.x * 256 + threadIdx.x;
  if (i >= n4) return;
  const float4 a = ((const float4*)x)[i];
  const float4 b = ((const float4*)y)[i];
  u16x4 oa, ob;
  oa[0] = f2bf(a.x); oa[1] = f2bf(a.y); oa[2] = f2bf(a.z); oa[3] = f2bf(a.w);
  ob[0] = f2bf(b.x); ob[1] = f2bf(b.y); ob[2] = f2bf(b.z); ob[3] = f2bf(b.w);
  ((u16x4*)ox)[i] = oa;
  ((u16x4*)oy)[i] = ob;
}

// ---------------------------------------------------------------------------
__global__ __launch_bounds__(256) void wtrans_k(const float* __restrict__ W,
                                                u16* __restrict__ WT) {
  const int tr = blockIdx.y * 64;
  const int tc = blockIdx.x * 64;
  __shared__ float T[64][65];
  const int t = threadIdx.x;
  const int r0 = t >> 4;
  const int c0 = (t & 15) * 4;
#pragma unroll
  for (int rr = 0; rr < 4; ++rr) {
    const int row = rr * 16 + r0;
    const float4 w = *(const float4*)&W[(size_t)(tr + row) * 512 + tc + c0];
    T[row][c0 + 0] = w.x; T[row][c0 + 1] = w.y;
    T[row][c0 + 2] = w.z; T[row][c0 + 3] = w.w;
  }
  __syncthreads();
#pragma unroll
  for (int rr = 0; rr < 4; ++rr) {
    const int orow = rr * 16 + r0;
    u16x4 o;
#pragma unroll
    for (int j = 0; j < 4; ++j) o[j] = f2bf(T[c0 + j][orow]);
    *(u16x4*)&WT[(size_t)(tc + orow) * 512 + tr + c0] = o;
  }
}

// ---------------------------------------------------------------------------
extern "C" void kernel_launch(void* const* d_in, const int* in_sizes, int n_in,
                              void* d_out, int out_size, void* d_ws,
                              size_t ws_size, hipStream_t stream) {
  const float* rgb = (const float*)d_in[0];
  const float* dep = (const float*)d_in[1];
  const float* Wq = (const float*)d_in[2];
  const float* bq = (const float*)d_in[3];
  const float* Wk = (const float*)d_in[4];
  const float* bk = (const float*)d_in[5];
  const float* Wv = (const float*)d_in[6];
  const float* bv = (const float*)d_in[7];
  float* out = (float*)d_out;

  const int B = 4, N = 4096, M = 4096, C = 512;
  const size_t nBNC = (size_t)B * N * C;
  const float scale = 0.044194173824159216f;  // 512^-0.5

  char* ws = (char*)d_ws;
  size_t off = 0;
  auto carve = [&](size_t bytes) -> void* {
    void* p = ws + off;
    off += (bytes + 255) & ~(size_t)255;
    return p;
  };
  u16* rgb_bf = (u16*)carve(nBNC * 2);
  u16* dep_bf = (u16*)carve(nBNC * 2);
  u16* WqT = (u16*)carve((size_t)C * C * 2);
  u16* WkT = (u16*)carve((size_t)C * C * 2);
  u16* WvT = (u16*)carve((size_t)C * C * 2);
  u16* Qb = (u16*)carve(nBNC * 2);
  u16* Kb = (u16*)carve(nBNC * 2);
  u16* Vt = (u16*)carve(nBNC * 2);
  u16* Sb = (u16*)carve((size_t)B * N * M * 2);  // 134 MB expS

  const long long strQ = (long long)N * C;  // 2,097,152
  const long long strS = (long long)N * M;  // 16,777,216
  const long long strV = (long long)C * M;  // 2,097,152

  // 0) conversions
  cvt_pair<<<8192, 256, 0, stream>>>(rgb, dep, rgb_bf, dep_bf, (int)(nBNC / 4));
  wtrans_k<<<dim3(8, 8), 256, 0, stream>>>(Wq, WqT);
  wtrans_k<<<dim3(8, 8), 256, 0, stream>>>(Wk, WkT);
  wtrans_k<<<dim3(8, 8), 256, 0, stream>>>(Wv, WvT);

  // 1) projections
  gemm32<128, 128, 1, 0, 4><<<dim3(4, 128, 1), 256, 0, stream>>>(
      rgb_bf, WqT, bq, Qb, 16384, 512, 512, 0, 0, 0, 1.f);
  gemm32<128, 128, 1, 0, 4><<<dim3(4, 128, 1), 256, 0, stream>>>(
      dep_bf, WkT, bk, Kb, 16384, 512, 512, 0, 0, 0, 1.f);
  gemm32<128, 128, 2, 0, 4><<<dim3(32, 4, 4), 256, 0, stream>>>(
      WvT, dep_bf, bv, Vt, 512, 4096, 512, 0, strQ, strV, 1.f);

  // 2) expS = exp(Q K^T * scale)  — 256^2 8-phase schedule
  gemm256_exp<<<dim3(16, 16, 4), 512, 0, stream>>>(Qb, Kb, Sb, strQ, strS,
                                                   scale);

  // 3) O = expS @ Vt^T / rowsum(expS)   (den via ones-MFMA, in-register)
  pv_gemm<<<dim3(2, 64, 4), 256, 0, stream>>>(Sb, Vt, out);
}

// Round 6
// 370.213 us; speedup vs baseline: 1.0461x; 1.0461x over previous
//
#include <hip/hip_runtime.h>
#include <hip/hip_bf16.h>
#include <stdint.h>

// CrossAttention (B=4, N=M=4096, C=512), fp32 in/out, bf16 MFMA internally.
// Round 10 (resubmit; prior round failed on GPU acquisition, kernel never
// ran): pv_gemm rebuilt in the gemm256_exp mold (the session's verified
// fast+race-free structure): TM128xTN256, BK=64, 8 waves, 3-buffer LDS,
// counted vmcnt(6), one barrier-pair per 24-MFMA body (64 bodies vs 128).
// R9 post-mortem: deep prefetch at BK=32 didn't help (all pipes <31% busy)
// -> per-body overhead (barriers/LDS issue) was the limit, so amortize it.
//   Q    = rgb @ WqT^T (+bq)          [16384 x 512]        gemm32
//   K    = dep @ WkT^T (+bk)          [16384 x 512]        gemm32
//   Vt   = WvT @ dep^T (+bv row)      per batch [512x4096] gemm32
//   expS = exp(Q K^T / sqrt(C))       per batch [4096^2]   gemm256_exp
//   O    = (expS @ Vt^T) / rowsum     per batch [4096x512] pv_gemm (NEW)

typedef unsigned short u16;
typedef __attribute__((ext_vector_type(8))) short bf16x8;
typedef __attribute__((ext_vector_type(16))) float f32x16;
typedef __attribute__((ext_vector_type(4))) unsigned short u16x4;

#define GLD_LDS16(g, l)                                                        \
  __builtin_amdgcn_global_load_lds(                                            \
      (const __attribute__((address_space(1))) unsigned int*)(g),              \
      (__attribute__((address_space(3))) unsigned int*)(l), 16, 0, 0)

__device__ __forceinline__ u16 f2bf(float f) {  // RNE f32 -> bf16
  unsigned x = __float_as_uint(f);
  return (u16)((x + 0x7fffu + ((x >> 16) & 1u)) >> 16);
}
__device__ __forceinline__ float bf2f(short s) {
  return __uint_as_float((unsigned)(unsigned short)s << 16);
}

// ---------------------------------------------------------------------------
// GEMM: C[M,N] = A[M,K]*B[N,K]^T, bf16 in, fp32 acc, 32x32x16 MFMA.
// 256 thr / 4 waves (2x2), TM x TN tile, BK=32, double-buffered LDS, one
// barrier per iter. XOR bank swizzle on 16-B k-chunks (R3: 0 conflicts).
// OUT_MODE: 0 = bf16, 1 = fp32. BIAS_MODE: 0 none, 1 bias[col], 2 bias[row].
// ---------------------------------------------------------------------------
template <int TM, int TN, int BIAS_MODE, int OUT_MODE, int MINW>
__global__ __launch_bounds__(256, MINW) void gemm32(
    const u16* __restrict__ A, const u16* __restrict__ Bm,
    const float* __restrict__ bias, void* __restrict__ Cv, int M, int N, int K,
    long long sAb, long long sBb, long long sCb, float scale) {
  constexpr int WROWS = TM / 2;
  constexpr int WCOLS = TN / 2;
  constexpr int MSUB = WROWS / 32;
  constexpr int NSUB = WCOLS / 32;
  constexpr int CA = TM / 64;  // A 16-row chunks per wave
  constexpr int CB = TN / 64;  // B 16-row chunks per wave

  const int bz = blockIdx.z;
  A += (size_t)bz * sAb;
  Bm += (size_t)bz * sBb;

  const int bm = blockIdx.y * TM;
  const int bn = blockIdx.x * TN;

  __shared__ u16 As[2][TM * 32];
  __shared__ u16 Bs[2][TN * 32];

  const int tid = threadIdx.x;
  const int wave = tid >> 6;
  const int lane = tid & 63;
  const int ln31 = lane & 31;
  const int half = lane >> 5;
  const int wr = wave >> 1;
  const int wc = wave & 1;

  const int rowA = lane >> 2;
  const int swz = ((lane & 3) ^ ((rowA + (rowA >> 2)) & 3)) * 8;
  const int gl = (ln31 + (ln31 >> 2)) & 3;

  f32x16 acc[MSUB][NSUB] = {};

  auto stage = [&](int buf, int k0) {
#pragma unroll
    for (int r = 0; r < CA; ++r) {
      const int ch = wave * CA + r;
      GLD_LDS16(A + (size_t)(bm + ch * 16 + rowA) * K + k0 + swz,
                As[buf] + ch * 16 * 32);
    }
#pragma unroll
    for (int r = 0; r < CB; ++r) {
      const int ch = wave * CB + r;
      GLD_LDS16(Bm + (size_t)(bn + ch * 16 + rowA) * K + k0 + swz,
                Bs[buf] + ch * 16 * 32);
    }
  };

  const int niter = K >> 5;
  stage(0, 0);
  for (int it = 0; it < niter; ++it) {
    __syncthreads();  // publishes buf it&1 (vmcnt drained here)
    if (it + 1 < niter) stage((it + 1) & 1, (it + 1) * 32);
    const int buf = it & 1;
#pragma unroll
    for (int kc = 0; kc < 2; ++kc) {
      const int p = ((kc * 2 + half) ^ gl) * 8;
      bf16x8 af[MSUB], bfv[NSUB];
#pragma unroll
      for (int mt = 0; mt < MSUB; ++mt)
        af[mt] =
            *(const bf16x8*)&As[buf][(wr * WROWS + mt * 32 + ln31) * 32 + p];
#pragma unroll
      for (int nt = 0; nt < NSUB; ++nt)
        bfv[nt] =
            *(const bf16x8*)&Bs[buf][(wc * WCOLS + nt * 32 + ln31) * 32 + p];
#pragma unroll
      for (int mt = 0; mt < MSUB; ++mt)
#pragma unroll
        for (int nt = 0; nt < NSUB; ++nt)
          acc[mt][nt] = __builtin_amdgcn_mfma_f32_32x32x16_bf16(
              af[mt], bfv[nt], acc[mt][nt], 0, 0, 0);
    }
  }

  // Epilogue. 32x32 C/D layout: col = lane&31, row = (r&3)+8*(r>>2)+4*half.
  const int crow0 = bm + wr * WROWS + 4 * half;
  const int ccol0 = bn + wc * WCOLS + ln31;
#pragma unroll
  for (int mt = 0; mt < MSUB; ++mt) {
#pragma unroll
    for (int nt = 0; nt < NSUB; ++nt) {
      const int col = ccol0 + nt * 32;
#pragma unroll
      for (int r = 0; r < 16; ++r) {
        const int row = crow0 + mt * 32 + (r & 3) + 8 * (r >> 2);
        float v = acc[mt][nt][r];
        if constexpr (BIAS_MODE == 1) v += bias[col];
        if constexpr (BIAS_MODE == 2) v += bias[row];
        const size_t idx = (size_t)bz * (size_t)sCb + (size_t)row * N + col;
        if constexpr (OUT_MODE == 0)
          ((u16*)Cv)[idx] = f2bf(v);
        else if constexpr (OUT_MODE == 1)
          ((float*)Cv)[idx] = v;
        else
          ((u16*)Cv)[idx] = f2bf(__expf(v * scale));
      }
    }
  }
}

// ---------------------------------------------------------------------------
// gemm256_exp: S[4096,4096] = exp(scale * Q[4096,512] K[4096,512]^T) in bf16.
// 256x256 tile, BK=64, 512 thr / 8 waves (2M x 4N), per-wave 128x64 output.
// 4 quadrant-phases per K-tile; counted vmcnt 4/5/6/3 (never 0 mid-loop).
// Verified passing (incl. replay tripwire) R7-R9. Unchanged.
// ---------------------------------------------------------------------------
#define XA_STGA(buf, j, k0)                                                    \
  GLD_LDS16(Ag + (size_t)((j) * 32 + (wv & 3) * 8 + (wv >> 2) * 128 + rlane) * \
                    512 +                                                      \
                (k0) + swz8,                                                   \
            &As[buf][((j) * 32 + (wv & 3) * 8 + (wv >> 2) * 128) * 64])
#define XA_STGB(buf, j, k0)                                                    \
  GLD_LDS16(Bg + (size_t)((j) * 64 + wv * 8 + rlane) * 512 + (k0) + swz8,      \
            &Bs[buf][((j) * 64 + wv * 8) * 64])

#define XA_PHASE(F, NV, PFS)                                                   \
  {                                                                            \
    bf16x8 af[4];                                                              \
    {                                                                          \
      const int arow = (wm * 128 + (F) * 32 + ln31) * 64;                      \
      _Pragma("unroll") for (int k = 0; k < 4; ++k) af[k] =                    \
          *(const bf16x8*)&As[p][arow + (((2 * k + half) ^ s7) << 3)];         \
    }                                                                          \
    if ((F) == 0) {                                                            \
      _Pragma("unroll") for (int n = 0; n < 2; ++n) {                          \
        const int brow = (wn * 64 + n * 32 + ln31) * 64;                       \
        _Pragma("unroll") for (int k = 0; k < 4; ++k) bfr[n][k] =              \
            *(const bf16x8*)&Bs[p][brow + (((2 * k + half) ^ s7) << 3)];       \
      }                                                                        \
    }                                                                          \
    PFS;                                                                       \
    __builtin_amdgcn_s_barrier();                                              \
    asm volatile("s_waitcnt lgkmcnt(0)" ::: "memory");                         \
    __builtin_amdgcn_sched_barrier(0);                                         \
    __builtin_amdgcn_s_setprio(1);                                             \
    _Pragma("unroll") for (int k = 0; k < 4; ++k) {                            \
      acc[F][0] = __builtin_amdgcn_mfma_f32_32x32x16_bf16(af[k], bfr[0][k],    \
                                                          acc[F][0], 0, 0, 0); \
      acc[F][1] = __builtin_amdgcn_mfma_f32_32x32x16_bf16(af[k], bfr[1][k],    \
                                                          acc[F][1], 0, 0, 0); \
    }                                                                          \
    __builtin_amdgcn_s_setprio(0);                                             \
    asm volatile("s_waitcnt vmcnt(" NV ")" ::: "memory");                      \
    __builtin_amdgcn_s_barrier();                                              \
    asm volatile("" ::: "memory");                                             \
  }

__global__ __launch_bounds__(512, 2) void gemm256_exp(
    const u16* __restrict__ Qm, const u16* __restrict__ Km,
    u16* __restrict__ Sout, long long sAb, long long sSb, float scale) {
  const int bz = blockIdx.z;
  const int bm = blockIdx.y * 256;
  const int bn = blockIdx.x * 256;
  const u16* Ag = Qm + (size_t)bz * (size_t)sAb + (size_t)bm * 512;
  const u16* Bg = Km + (size_t)bz * (size_t)sAb + (size_t)bn * 512;

  __shared__ u16 As[2][256 * 64];  // 64 KB
  __shared__ u16 Bs[2][256 * 64];  // 64 KB

  const int tid = threadIdx.x;
  const int wv = tid >> 6;    // wave 0..7
  const int lane = tid & 63;
  const int ln31 = lane & 31;
  const int half = lane >> 5;
  const int wm = wv >> 2;     // 0..1: 128-row half
  const int wn = wv & 3;      // 0..3: 64-col group
  const int rlane = lane >> 3;                 // staged row within 8-row chunk
  const int swz8 = ((lane & 7) ^ rlane) << 3;  // pre-swizzled global k-offset
  const int s7 = ln31 & 7;                     // ds_read swizzle key

  f32x16 acc[4][2] = {};
  bf16x8 bfr[2][4];

  // prologue: stage tile 0 into buf 0 (issue order B0..B3, A0..A3)
#pragma unroll
  for (int j = 0; j < 4; ++j) XA_STGB(0, j, 0);
#pragma unroll
  for (int j = 0; j < 4; ++j) XA_STGA(0, j, 0);
  asm volatile("s_waitcnt vmcnt(3)" ::: "memory");  // B0-3 + A0 landed
  __builtin_amdgcn_s_barrier();
  asm volatile("" ::: "memory");

  for (int t = 0; t < 7; ++t) {  // K = 512 -> 8 tiles of 64
    const int p = t & 1;
    const int q = p ^ 1;
    const int kn = (t + 1) << 6;
    XA_PHASE(0, "4", { XA_STGB(q, 0, kn); XA_STGB(q, 1, kn); });
    XA_PHASE(1, "5", { XA_STGB(q, 2, kn); XA_STGB(q, 3, kn); });
    XA_PHASE(2, "6", { XA_STGA(q, 0, kn); XA_STGA(q, 1, kn); });
    XA_PHASE(3, "3", { XA_STGA(q, 2, kn); XA_STGA(q, 3, kn); });
  }
  {  // last tile: no prefetch, drain progressively
    const int p = 1;
    XA_PHASE(0, "2", {});
    XA_PHASE(1, "1", {});
    XA_PHASE(2, "0", {});
    XA_PHASE(3, "0", {});
  }

  // epilogue: exp + bf16 store. 32x32 layout: col=lane&31, row=(r&3)+8*(r>>2)+4*half.
  const size_t ob = (size_t)bz * (size_t)sSb;
  const int c0 = bn + wn * 64 + ln31;
  const int r0 = bm + wm * 128 + 4 * half;
#pragma unroll
  for (int m = 0; m < 4; ++m) {
#pragma unroll
    for (int n = 0; n < 2; ++n) {
      const int col = c0 + n * 32;
#pragma unroll
      for (int r = 0; r < 16; ++r) {
        const int row = r0 + m * 32 + (r & 3) + 8 * (r >> 2);
        Sout[ob + (size_t)row * 4096 + col] = f2bf(__expf(acc[m][n][r] * scale));
      }
    }
  }
}

// ---------------------------------------------------------------------------
// PV: O[4096 x 512] = (expS @ Vt^T) / rowsum, per batch. Round 10 structure:
// TM=128 x TN=256, BK=64, 512 thr / 8 waves (2M x 4N; per wave 64x64 out =
// acc[2][2] + dacc[2] ones-MFMA rowsum). 3 LDS buffers (144 KB, 1 block/CU,
// 2 waves/SIMD). 64 bodies; per body (R9-verified ordering, re-derived
// counts): {stage 6 gld of tile t+2; 16 ds_read_b128 of tile t; barrier;
// lgkmcnt(0)+sched_barrier(0); setprio(1); 24 MFMA; setprio(0);
// vmcnt(6); barrier; fence}.
//  WAR: buffer (t+2)%3 was read in body t-1; every wave's reads completed at
//    its body-t-1 lgkmcnt(0), which precedes the body-t-1 end barrier.
//  RAW: end of body t has t+1(6 oldest) + t+2(6) in flight; vmcnt(6) drains
//    t+1 in every wave; barrier publishes. Tail: body 62 "0", body 63 none.
// LDS addressing = gemm256_exp's verified 128-B-row XOR swizzle.
// ---------------------------------------------------------------------------
#define PV_BODY(IT, NV, DO_STAGE, DO_TAIL)                                     \
  {                                                                            \
    const int buf = (IT) % 3;                                                  \
    if (DO_STAGE) stage(((IT) + 2) % 3, ((IT) + 2) * 64);                      \
    bf16x8 af[4][2], bfv[4][2];                                                \
    _Pragma("unroll") for (int k = 0; k < 4; ++k) {                            \
      const int p = ((2 * k + half) ^ s7) << 3;                                \
      _Pragma("unroll") for (int mt = 0; mt < 2; ++mt)                         \
        af[k][mt] =                                                            \
            *(const bf16x8*)&As[buf][(wm * 64 + mt * 32 + ln31) * 64 + p];     \
      _Pragma("unroll") for (int nt = 0; nt < 2; ++nt)                         \
        bfv[k][nt] =                                                           \
            *(const bf16x8*)&Bs[buf][(wn * 64 + nt * 32 + ln31) * 64 + p];     \
    }                                                                          \
    __builtin_amdgcn_s_barrier();                                              \
    asm volatile("s_waitcnt lgkmcnt(0)" ::: "memory");                         \
    __builtin_amdgcn_sched_barrier(0);                                         \
    __builtin_amdgcn_s_setprio(1);                                             \
    _Pragma("unroll") for (int k = 0; k < 4; ++k) {                            \
      _Pragma("unroll") for (int mt = 0; mt < 2; ++mt) {                       \
        dacc[mt] = __builtin_amdgcn_mfma_f32_32x32x16_bf16(                    \
            af[k][mt], onesv, dacc[mt], 0, 0, 0);                              \
        _Pragma("unroll") for (int nt = 0; nt < 2; ++nt)                       \
          acc[mt][nt] = __builtin_amdgcn_mfma_f32_32x32x16_bf16(               \
              af[k][mt], bfv[k][nt], acc[mt][nt], 0, 0, 0);                    \
      }                                                                        \
    }                                                                          \
    __builtin_amdgcn_s_setprio(0);                                             \
    if (DO_TAIL) {                                                             \
      asm volatile("s_waitcnt vmcnt(" NV ")" ::: "memory");                    \
      __builtin_amdgcn_s_barrier();                                            \
      asm volatile("" ::: "memory");                                           \
    }                                                                          \
  }

__global__ __launch_bounds__(512, 2) void pv_gemm(
    const u16* __restrict__ P, const u16* __restrict__ Vt,
    float* __restrict__ O) {
  const int bz = blockIdx.z;
  const u16* A = P + (size_t)bz * (4096ull * 4096ull);
  const u16* B = Vt + (size_t)bz * (512ull * 4096ull);
  float* Ob = O + (size_t)bz * (4096ull * 512ull);

  const int bm = blockIdx.y * 128;  // q-row slab
  const int bn = blockIdx.x * 256;  // d half

  __shared__ u16 As[3][128 * 64];  // 3 x 16 KB
  __shared__ u16 Bs[3][256 * 64];  // 3 x 32 KB  (total 144 KB, 1 block/CU)

  const int tid = threadIdx.x;
  const int wv = tid >> 6;  // wave 0..7
  const int lane = tid & 63;
  const int ln31 = lane & 31;
  const int half = lane >> 5;
  const int wm = wv >> 2;  // 0..1: 64-row half
  const int wn = wv & 3;   // 0..3: 64-col group
  const int rlane = lane >> 3;                 // staged row within 8-row chunk
  const int swz8 = ((lane & 7) ^ rlane) << 3;  // pre-swizzled global k-offset
  const int s7 = ln31 & 7;                     // ds_read swizzle key

  f32x16 acc[2][2] = {};
  f32x16 dacc[2] = {};
  bf16x8 onesv;
#pragma unroll
  for (int j = 0; j < 8; ++j) onesv[j] = (short)0x3F80;  // bf16 1.0

  auto stage = [&](int buf, int k0) {
    // A: 16 chunks of 8 rows (HBM-cold Sb — issue first), 2 per wave.
#pragma unroll
    for (int r = 0; r < 2; ++r) {
      const int ch = wv * 2 + r;
      GLD_LDS16(A + (size_t)(bm + ch * 8 + rlane) * 4096 + k0 + swz8,
                As[buf] + ch * 8 * 64);
    }
    // B: 32 chunks of 8 rows (L2-resident Vt), 4 per wave.
#pragma unroll
    for (int r = 0; r < 4; ++r) {
      const int ch = wv * 4 + r;
      GLD_LDS16(B + (size_t)(bn + ch * 8 + rlane) * 4096 + k0 + swz8,
                Bs[buf] + ch * 8 * 64);
    }
  };

  // prologue: stage tiles 0,1 (12 loads in flight); wait tile 0; publish.
  stage(0, 0);
  stage(1, 64);
  asm volatile("s_waitcnt vmcnt(6)" ::: "memory");
  __builtin_amdgcn_s_barrier();
  asm volatile("" ::: "memory");

  for (int it = 0; it < 62; ++it) PV_BODY(it, "6", true, true);
  PV_BODY(62, "0", false, true);
  PV_BODY(63, "0", false, false);  // last body: no tail barrier needed

  // Epilogue: rd = 1/dacc — same C/D row mapping as acc, zero cross-lane.
  const int crow0 = bm + wm * 64 + 4 * half;
  const int ccol0 = bn + wn * 64 + ln31;
#pragma unroll
  for (int mt = 0; mt < 2; ++mt) {
#pragma unroll
    for (int r = 0; r < 16; ++r) {
      const int rl = crow0 + mt * 32 + (r & 3) + 8 * (r >> 2);
      const float rd = 1.0f / dacc[mt][r];
#pragma unroll
      for (int nt = 0; nt < 2; ++nt)
        Ob[(size_t)rl * 512 + ccol0 + nt * 32] = acc[mt][nt][r] * rd;
    }
  }
}

// ---------------------------------------------------------------------------
__global__ __launch_bounds__(256) void cvt_pair(const float* __restrict__ x,
                                                const float* __restrict__ y,
                                                u16* __restrict__ ox,
                                                u16* __restrict__ oy, int n4) {
  const int i = blockIdx.x * 256 + threadIdx.x;
  if (i >= n4) return;
  const float4 a = ((const float4*)x)[i];
  const float4 b = ((const float4*)y)[i];
  u16x4 oa, ob;
  oa[0] = f2bf(a.x); oa[1] = f2bf(a.y); oa[2] = f2bf(a.z); oa[3] = f2bf(a.w);
  ob[0] = f2bf(b.x); ob[1] = f2bf(b.y); ob[2] = f2bf(b.z); ob[3] = f2bf(b.w);
  ((u16x4*)ox)[i] = oa;
  ((u16x4*)oy)[i] = ob;
}

// ---------------------------------------------------------------------------
// 3 weight transposes in one launch (grid z selects the matrix).
__global__ __launch_bounds__(256) void wtrans_k3(
    const float* __restrict__ Wq, const float* __restrict__ Wk,
    const float* __restrict__ Wv, u16* __restrict__ WqT,
    u16* __restrict__ WkT, u16* __restrict__ WvT) {
  const int z = blockIdx.z;
  const float* W = z == 0 ? Wq : (z == 1 ? Wk : Wv);
  u16* WT = z == 0 ? WqT : (z == 1 ? WkT : WvT);
  const int tr = blockIdx.y * 64;
  const int tc = blockIdx.x * 64;
  __shared__ float T[64][65];
  const int t = threadIdx.x;
  const int r0 = t >> 4;
  const int c0 = (t & 15) * 4;
#pragma unroll
  for (int rr = 0; rr < 4; ++rr) {
    const int row = rr * 16 + r0;
    const float4 w = *(const float4*)&W[(size_t)(tr + row) * 512 + tc + c0];
    T[row][c0 + 0] = w.x; T[row][c0 + 1] = w.y;
    T[row][c0 + 2] = w.z; T[row][c0 + 3] = w.w;
  }
  __syncthreads();
#pragma unroll
  for (int rr = 0; rr < 4; ++rr) {
    const int orow = rr * 16 + r0;
    u16x4 o;
#pragma unroll
    for (int j = 0; j < 4; ++j) o[j] = f2bf(T[c0 + j][orow]);
    *(u16x4*)&WT[(size_t)(tc + orow) * 512 + tr + c0] = o;
  }
}

// ---------------------------------------------------------------------------
extern "C" void kernel_launch(void* const* d_in, const int* in_sizes, int n_in,
                              void* d_out, int out_size, void* d_ws,
                              size_t ws_size, hipStream_t stream) {
  const float* rgb = (const float*)d_in[0];
  const float* dep = (const float*)d_in[1];
  const float* Wq = (const float*)d_in[2];
  const float* bq = (const float*)d_in[3];
  const float* Wk = (const float*)d_in[4];
  const float* bk = (const float*)d_in[5];
  const float* Wv = (const float*)d_in[6];
  const float* bv = (const float*)d_in[7];
  float* out = (float*)d_out;

  const int B = 4, N = 4096, M = 4096, C = 512;
  const size_t nBNC = (size_t)B * N * C;
  const float scale = 0.044194173824159216f;  // 512^-0.5

  char* ws = (char*)d_ws;
  size_t off = 0;
  auto carve = [&](size_t bytes) -> void* {
    void* p = ws + off;
    off += (bytes + 255) & ~(size_t)255;
    return p;
  };
  u16* rgb_bf = (u16*)carve(nBNC * 2);
  u16* dep_bf = (u16*)carve(nBNC * 2);
  u16* WqT = (u16*)carve((size_t)C * C * 2);
  u16* WkT = (u16*)carve((size_t)C * C * 2);
  u16* WvT = (u16*)carve((size_t)C * C * 2);
  u16* Qb = (u16*)carve(nBNC * 2);
  u16* Kb = (u16*)carve(nBNC * 2);
  u16* Vt = (u16*)carve(nBNC * 2);
  u16* Sb = (u16*)carve((size_t)B * N * M * 2);  // 134 MB expS

  const long long strQ = (long long)N * C;  // 2,097,152
  const long long strS = (long long)N * M;  // 16,777,216
  const long long strV = (long long)C * M;  // 2,097,152

  // 0) conversions
  cvt_pair<<<8192, 256, 0, stream>>>(rgb, dep, rgb_bf, dep_bf, (int)(nBNC / 4));
  wtrans_k3<<<dim3(8, 8, 3), 256, 0, stream>>>(Wq, Wk, Wv, WqT, WkT, WvT);

  // 1) projections
  gemm32<128, 128, 1, 0, 4><<<dim3(4, 128, 1), 256, 0, stream>>>(
      rgb_bf, WqT, bq, Qb, 16384, 512, 512, 0, 0, 0, 1.f);
  gemm32<128, 128, 1, 0, 4><<<dim3(4, 128, 1), 256, 0, stream>>>(
      dep_bf, WkT, bk, Kb, 16384, 512, 512, 0, 0, 0, 1.f);
  gemm32<128, 128, 2, 0, 4><<<dim3(32, 4, 4), 256, 0, stream>>>(
      WvT, dep_bf, bv, Vt, 512, 4096, 512, 0, strQ, strV, 1.f);

  // 2) expS = exp(Q K^T * scale)  — 256^2 8-phase schedule
  gemm256_exp<<<dim3(16, 16, 4), 512, 0, stream>>>(Qb, Kb, Sb, strQ, strS,
                                                   scale);

  // 3) O = expS @ Vt^T / rowsum(expS)   (den via ones-MFMA, in-register)
  pv_gemm<<<dim3(2, 32, 4), 512, 0, stream>>>(Sb, Vt, out);
}

// Round 12
// 365.279 us; speedup vs baseline: 1.0602x; 1.0135x over previous
//
#include <hip/hip_runtime.h>
#include <hip/hip_bf16.h>
#include <stdint.h>

// CrossAttention (B=4, N=M=4096, C=512), fp32 in/out, bf16 MFMA internally.
// Round 11 (5th resubmit; five infra failures in a row, kernel never ran):
// pv_gemm only — (a) two-plane LDS layout (64-B rows, R2's
// measured-zero-conflict swizzle) kills the exact +4cyc/ds_read_b128 bank
// conflict (8.39M = 4 x 2^21 in R10); (b) single barrier per body (WAR/RAW
// re-proven: lgkmcnt(0) before the one barrier covers reads; vmcnt(6)
// before it covers the staged tile). Everything else frozen.
//   Q    = rgb @ WqT^T (+bq)          [16384 x 512]        gemm32
//   K    = dep @ WkT^T (+bk)          [16384 x 512]        gemm32
//   Vt   = WvT @ dep^T (+bv row)      per batch [512x4096] gemm32
//   expS = exp(Q K^T / sqrt(C))       per batch [4096^2]   gemm256_exp
//   O    = (expS @ Vt^T) / rowsum     per batch [4096x512] pv_gemm (v3)

typedef unsigned short u16;
typedef __attribute__((ext_vector_type(8))) short bf16x8;
typedef __attribute__((ext_vector_type(16))) float f32x16;
typedef __attribute__((ext_vector_type(4))) unsigned short u16x4;

#define GLD_LDS16(g, l)                                                        \
  __builtin_amdgcn_global_load_lds(                                            \
      (const __attribute__((address_space(1))) unsigned int*)(g),              \
      (__attribute__((address_space(3))) unsigned int*)(l), 16, 0, 0)

__device__ __forceinline__ u16 f2bf(float f) {  // RNE f32 -> bf16
  unsigned x = __float_as_uint(f);
  return (u16)((x + 0x7fffu + ((x >> 16) & 1u)) >> 16);
}
__device__ __forceinline__ float bf2f(short s) {
  return __uint_as_float((unsigned)(unsigned short)s << 16);
}

// ---------------------------------------------------------------------------
// GEMM: C[M,N] = A[M,K]*B[N,K]^T, bf16 in, fp32 acc, 32x32x16 MFMA.
// 256 thr / 4 waves (2x2), TM x TN tile, BK=32, double-buffered LDS, one
// barrier per iter. XOR bank swizzle on 16-B k-chunks (R3: 0 conflicts).
// OUT_MODE: 0 = bf16, 1 = fp32. BIAS_MODE: 0 none, 1 bias[col], 2 bias[row].
// ---------------------------------------------------------------------------
template <int TM, int TN, int BIAS_MODE, int OUT_MODE, int MINW>
__global__ __launch_bounds__(256, MINW) void gemm32(
    const u16* __restrict__ A, const u16* __restrict__ Bm,
    const float* __restrict__ bias, void* __restrict__ Cv, int M, int N, int K,
    long long sAb, long long sBb, long long sCb, float scale) {
  constexpr int WROWS = TM / 2;
  constexpr int WCOLS = TN / 2;
  constexpr int MSUB = WROWS / 32;
  constexpr int NSUB = WCOLS / 32;
  constexpr int CA = TM / 64;  // A 16-row chunks per wave
  constexpr int CB = TN / 64;  // B 16-row chunks per wave

  const int bz = blockIdx.z;
  A += (size_t)bz * sAb;
  Bm += (size_t)bz * sBb;

  const int bm = blockIdx.y * TM;
  const int bn = blockIdx.x * TN;

  __shared__ u16 As[2][TM * 32];
  __shared__ u16 Bs[2][TN * 32];

  const int tid = threadIdx.x;
  const int wave = tid >> 6;
  const int lane = tid & 63;
  const int ln31 = lane & 31;
  const int half = lane >> 5;
  const int wr = wave >> 1;
  const int wc = wave & 1;

  const int rowA = lane >> 2;
  const int swz = ((lane & 3) ^ ((rowA + (rowA >> 2)) & 3)) * 8;
  const int gl = (ln31 + (ln31 >> 2)) & 3;

  f32x16 acc[MSUB][NSUB] = {};

  auto stage = [&](int buf, int k0) {
#pragma unroll
    for (int r = 0; r < CA; ++r) {
      const int ch = wave * CA + r;
      GLD_LDS16(A + (size_t)(bm + ch * 16 + rowA) * K + k0 + swz,
                As[buf] + ch * 16 * 32);
    }
#pragma unroll
    for (int r = 0; r < CB; ++r) {
      const int ch = wave * CB + r;
      GLD_LDS16(Bm + (size_t)(bn + ch * 16 + rowA) * K + k0 + swz,
                Bs[buf] + ch * 16 * 32);
    }
  };

  const int niter = K >> 5;
  stage(0, 0);
  for (int it = 0; it < niter; ++it) {
    __syncthreads();  // publishes buf it&1 (vmcnt drained here)
    if (it + 1 < niter) stage((it + 1) & 1, (it + 1) * 32);
    const int buf = it & 1;
#pragma unroll
    for (int kc = 0; kc < 2; ++kc) {
      const int p = ((kc * 2 + half) ^ gl) * 8;
      bf16x8 af[MSUB], bfv[NSUB];
#pragma unroll
      for (int mt = 0; mt < MSUB; ++mt)
        af[mt] =
            *(const bf16x8*)&As[buf][(wr * WROWS + mt * 32 + ln31) * 32 + p];
#pragma unroll
      for (int nt = 0; nt < NSUB; ++nt)
        bfv[nt] =
            *(const bf16x8*)&Bs[buf][(wc * WCOLS + nt * 32 + ln31) * 32 + p];
#pragma unroll
      for (int mt = 0; mt < MSUB; ++mt)
#pragma unroll
        for (int nt = 0; nt < NSUB; ++nt)
          acc[mt][nt] = __builtin_amdgcn_mfma_f32_32x32x16_bf16(
              af[mt], bfv[nt], acc[mt][nt], 0, 0, 0);
    }
  }

  // Epilogue. 32x32 C/D layout: col = lane&31, row = (r&3)+8*(r>>2)+4*half.
  const int crow0 = bm + wr * WROWS + 4 * half;
  const int ccol0 = bn + wc * WCOLS + ln31;
#pragma unroll
  for (int mt = 0; mt < MSUB; ++mt) {
#pragma unroll
    for (int nt = 0; nt < NSUB; ++nt) {
      const int col = ccol0 + nt * 32;
#pragma unroll
      for (int r = 0; r < 16; ++r) {
        const int row = crow0 + mt * 32 + (r & 3) + 8 * (r >> 2);
        float v = acc[mt][nt][r];
        if constexpr (BIAS_MODE == 1) v += bias[col];
        if constexpr (BIAS_MODE == 2) v += bias[row];
        const size_t idx = (size_t)bz * (size_t)sCb + (size_t)row * N + col;
        if constexpr (OUT_MODE == 0)
          ((u16*)Cv)[idx] = f2bf(v);
        else if constexpr (OUT_MODE == 1)
          ((float*)Cv)[idx] = v;
        else
          ((u16*)Cv)[idx] = f2bf(__expf(v * scale));
      }
    }
  }
}

// ---------------------------------------------------------------------------
// gemm256_exp: S[4096,4096] = exp(scale * Q[4096,512] K[4096,512]^T) in bf16.
// 256x256 tile, BK=64, 512 thr / 8 waves (2M x 4N), per-wave 128x64 output.
// 4 quadrant-phases per K-tile; counted vmcnt 4/5/6/3 (never 0 mid-loop).
// Verified passing (incl. replay tripwire) R7-R10. Unchanged.
// ---------------------------------------------------------------------------
#define XA_STGA(buf, j, k0)                                                    \
  GLD_LDS16(Ag + (size_t)((j) * 32 + (wv & 3) * 8 + (wv >> 2) * 128 + rlane) * \
                    512 +                                                      \
                (k0) + swz8,                                                   \
            &As[buf][((j) * 32 + (wv & 3) * 8 + (wv >> 2) * 128) * 64])
#define XA_STGB(buf, j, k0)                                                    \
  GLD_LDS16(Bg + (size_t)((j) * 64 + wv * 8 + rlane) * 512 + (k0) + swz8,      \
            &Bs[buf][((j) * 64 + wv * 8) * 64])

#define XA_PHASE(F, NV, PFS)                                                   \
  {                                                                            \
    bf16x8 af[4];                                                              \
    {                                                                          \
      const int arow = (wm * 128 + (F) * 32 + ln31) * 64;                      \
      _Pragma("unroll") for (int k = 0; k < 4; ++k) af[k] =                    \
          *(const bf16x8*)&As[p][arow + (((2 * k + half) ^ s7) << 3)];         \
    }                                                                          \
    if ((F) == 0) {                                                            \
      _Pragma("unroll") for (int n = 0; n < 2; ++n) {                          \
        const int brow = (wn * 64 + n * 32 + ln31) * 64;                       \
        _Pragma("unroll") for (int k = 0; k < 4; ++k) bfr[n][k] =              \
            *(const bf16x8*)&Bs[p][brow + (((2 * k + half) ^ s7) << 3)];       \
      }                                                                        \
    }                                                                          \
    PFS;                                                                       \
    __builtin_amdgcn_s_barrier();                                              \
    asm volatile("s_waitcnt lgkmcnt(0)" ::: "memory");                         \
    __builtin_amdgcn_sched_barrier(0);                                         \
    __builtin_amdgcn_s_setprio(1);                                             \
    _Pragma("unroll") for (int k = 0; k < 4; ++k) {                            \
      acc[F][0] = __builtin_amdgcn_mfma_f32_32x32x16_bf16(af[k], bfr[0][k],    \
                                                          acc[F][0], 0, 0, 0); \
      acc[F][1] = __builtin_amdgcn_mfma_f32_32x32x16_bf16(af[k], bfr[1][k],    \
                                                          acc[F][1], 0, 0, 0); \
    }                                                                          \
    __builtin_amdgcn_s_setprio(0);                                             \
    asm volatile("s_waitcnt vmcnt(" NV ")" ::: "memory");                      \
    __builtin_amdgcn_s_barrier();                                              \
    asm volatile("" ::: "memory");                                             \
  }

__global__ __launch_bounds__(512, 2) void gemm256_exp(
    const u16* __restrict__ Qm, const u16* __restrict__ Km,
    u16* __restrict__ Sout, long long sAb, long long sSb, float scale) {
  const int bz = blockIdx.z;
  const int bm = blockIdx.y * 256;
  const int bn = blockIdx.x * 256;
  const u16* Ag = Qm + (size_t)bz * (size_t)sAb + (size_t)bm * 512;
  const u16* Bg = Km + (size_t)bz * (size_t)sAb + (size_t)bn * 512;

  __shared__ u16 As[2][256 * 64];  // 64 KB
  __shared__ u16 Bs[2][256 * 64];  // 64 KB

  const int tid = threadIdx.x;
  const int wv = tid >> 6;    // wave 0..7
  const int lane = tid & 63;
  const int ln31 = lane & 31;
  const int half = lane >> 5;
  const int wm = wv >> 2;     // 0..1: 128-row half
  const int wn = wv & 3;      // 0..3: 64-col group
  const int rlane = lane >> 3;                 // staged row within 8-row chunk
  const int swz8 = ((lane & 7) ^ rlane) << 3;  // pre-swizzled global k-offset
  const int s7 = ln31 & 7;                     // ds_read swizzle key

  f32x16 acc[4][2] = {};
  bf16x8 bfr[2][4];

  // prologue: stage tile 0 into buf 0 (issue order B0..B3, A0..A3)
#pragma unroll
  for (int j = 0; j < 4; ++j) XA_STGB(0, j, 0);
#pragma unroll
  for (int j = 0; j < 4; ++j) XA_STGA(0, j, 0);
  asm volatile("s_waitcnt vmcnt(3)" ::: "memory");  // B0-3 + A0 landed
  __builtin_amdgcn_s_barrier();
  asm volatile("" ::: "memory");

  for (int t = 0; t < 7; ++t) {  // K = 512 -> 8 tiles of 64
    const int p = t & 1;
    const int q = p ^ 1;
    const int kn = (t + 1) << 6;
    XA_PHASE(0, "4", { XA_STGB(q, 0, kn); XA_STGB(q, 1, kn); });
    XA_PHASE(1, "5", { XA_STGB(q, 2, kn); XA_STGB(q, 3, kn); });
    XA_PHASE(2, "6", { XA_STGA(q, 0, kn); XA_STGA(q, 1, kn); });
    XA_PHASE(3, "3", { XA_STGA(q, 2, kn); XA_STGA(q, 3, kn); });
  }
  {  // last tile: no prefetch, drain progressively
    const int p = 1;
    XA_PHASE(0, "2", {});
    XA_PHASE(1, "1", {});
    XA_PHASE(2, "0", {});
    XA_PHASE(3, "0", {});
  }

  // epilogue: exp + bf16 store. 32x32 layout: col=lane&31, row=(r&3)+8*(r>>2)+4*half.
  const size_t ob = (size_t)bz * (size_t)sSb;
  const int c0 = bn + wn * 64 + ln31;
  const int r0 = bm + wm * 128 + 4 * half;
#pragma unroll
  for (int m = 0; m < 4; ++m) {
#pragma unroll
    for (int n = 0; n < 2; ++n) {
      const int col = c0 + n * 32;
#pragma unroll
      for (int r = 0; r < 16; ++r) {
        const int row = r0 + m * 32 + (r & 3) + 8 * (r >> 2);
        Sout[ob + (size_t)row * 4096 + col] = f2bf(__expf(acc[m][n][r] * scale));
      }
    }
  }
}

// ---------------------------------------------------------------------------
// PV v3: O[4096 x 512] = (expS @ Vt^T) / rowsum, per batch.
// TM=128 x TN=256, BK=64, 512 thr / 8 waves (2M x 4N; per wave 64x64 out).
// Round 11 changes vs R10:
//  (a) two-plane LDS layout: BK=64 stored as 2 planes of 32 u16/row (64-B
//      row stride) with R2's measured-zero-conflict swizzle per plane.
//      R10's 128-B rows made bank(row,chunk) row-independent -> exactly
//      +4 cyc per ds_read_b128 (8.39M = 4 x 2^21 measured).
//  (b) ONE barrier per body: {stage(t+2); 16 ds_read of t; lgkmcnt(0)+
//      sched_barrier(0); setprio(1) 24 MFMA setprio(0); vmcnt(6); barrier}.
//      WAR: reads of buf (t+2)%3 done at body t-1's lgkmcnt(0), before its
//      barrier, before this stage. RAW: body t-1's vmcnt(6) left only
//      stage(t+1) in flight -> stage(t) landed before barrier released t.
// 3 buffers x 48 KB = 144 KB, 1 block/CU. Tail: body 62 vmcnt(0), 63 none.
// den via ones-MFMA (numerics verified R8-R10).
// ---------------------------------------------------------------------------
#define PV_BODY(IT, NV, DO_STAGE, DO_TAIL)                                     \
  {                                                                            \
    const int buf = (IT) % 3;                                                  \
    if (DO_STAGE) stage(((IT) + 2) % 3, ((IT) + 2) * 64);                      \
    bf16x8 af[4][2], bfv[4][2];                                                \
    _Pragma("unroll") for (int pl = 0; pl < 2; ++pl) {                         \
      _Pragma("unroll") for (int kc = 0; kc < 2; ++kc) {                       \
        const int ks = pl * 2 + kc;                                            \
        const int p = ((kc * 2 + half) ^ gl) * 8;                              \
        _Pragma("unroll") for (int mt = 0; mt < 2; ++mt)                       \
          af[ks][mt] = *(const bf16x8*)&As[buf][(pl * 128 + wm * 64 +          \
                                                 mt * 32 + ln31) * 32 + p];    \
        _Pragma("unroll") for (int nt = 0; nt < 2; ++nt)                       \
          bfv[ks][nt] = *(const bf16x8*)&Bs[buf][(pl * 256 + wn * 64 +         \
                                                  nt * 32 + ln31) * 32 + p];   \
      }                                                                        \
    }                                                                          \
    asm volatile("s_waitcnt lgkmcnt(0)" ::: "memory");                         \
    __builtin_amdgcn_sched_barrier(0);                                         \
    __builtin_amdgcn_s_setprio(1);                                             \
    _Pragma("unroll") for (int ks = 0; ks < 4; ++ks) {                         \
      _Pragma("unroll") for (int mt = 0; mt < 2; ++mt) {                       \
        dacc[mt] = __builtin_amdgcn_mfma_f32_32x32x16_bf16(                    \
            af[ks][mt], onesv, dacc[mt], 0, 0, 0);                             \
        _Pragma("unroll") for (int nt = 0; nt < 2; ++nt)                       \
          acc[mt][nt] = __builtin_amdgcn_mfma_f32_32x32x16_bf16(               \
              af[ks][mt], bfv[ks][nt], acc[mt][nt], 0, 0, 0);                  \
      }                                                                        \
    }                                                                          \
    __builtin_amdgcn_s_setprio(0);                                             \
    if (DO_TAIL) {                                                             \
      asm volatile("s_waitcnt vmcnt(" NV ")" ::: "memory");                    \
      __builtin_amdgcn_s_barrier();                                            \
      asm volatile("" ::: "memory");                                           \
    }                                                                          \
  }

__global__ __launch_bounds__(512, 2) void pv_gemm(
    const u16* __restrict__ P, const u16* __restrict__ Vt,
    float* __restrict__ O) {
  const int bz = blockIdx.z;
  const u16* A = P + (size_t)bz * (4096ull * 4096ull);
  const u16* B = Vt + (size_t)bz * (512ull * 4096ull);
  float* Ob = O + (size_t)bz * (4096ull * 512ull);

  const int bm = blockIdx.y * 128;  // q-row slab
  const int bn = blockIdx.x * 256;  // d half

  // two-plane layout: [buf][plane*ROWS + row][32 u16]
  __shared__ u16 As[3][2 * 128 * 32];  // 3 x 16 KB
  __shared__ u16 Bs[3][2 * 256 * 32];  // 3 x 32 KB  (144 KB total, 1 blk/CU)

  const int tid = threadIdx.x;
  const int wv = tid >> 6;  // wave 0..7
  const int lane = tid & 63;
  const int ln31 = lane & 31;
  const int half = lane >> 5;
  const int wm = wv >> 2;  // 0..1: 64-row half
  const int wn = wv & 3;   // 0..3: 64-col group

  // R2-verified zero-conflict swizzle (64-B rows, 4 chunks of 16 B):
  const int rowA = lane >> 2;  // staged row within 16-row group
  const int swz = ((lane & 3) ^ ((rowA + (rowA >> 2)) & 3)) * 8;
  const int gl = (ln31 + (ln31 >> 2)) & 3;

  f32x16 acc[2][2] = {};
  f32x16 dacc[2] = {};
  bf16x8 onesv;
#pragma unroll
  for (int j = 0; j < 8; ++j) onesv[j] = (short)0x3F80;  // bf16 1.0

  auto stage = [&](int buf, int k0) {
    // A: 16 gld (2/wave): id -> plane (id>>3), 16-row group (id&7).
#pragma unroll
    for (int r = 0; r < 2; ++r) {
      const int id = wv * 2 + r;
      const int pl = id >> 3, rg = id & 7;
      GLD_LDS16(A + (size_t)(bm + rg * 16 + rowA) * 4096 + k0 + pl * 32 + swz,
                As[buf] + (pl * 128 + rg * 16) * 32);
    }
    // B: 32 gld (4/wave): id -> plane (id>>4), 16-row group (id&15).
#pragma unroll
    for (int r = 0; r < 4; ++r) {
      const int id = wv * 4 + r;
      const int pl = id >> 4, rg = id & 15;
      GLD_LDS16(B + (size_t)(bn + rg * 16 + rowA) * 4096 + k0 + pl * 32 + swz,
                Bs[buf] + (pl * 256 + rg * 16) * 32);
    }
  };

  // prologue: stage tiles 0,1 (12 loads in flight); wait tile 0; publish.
  stage(0, 0);
  stage(1, 64);
  asm volatile("s_waitcnt vmcnt(6)" ::: "memory");
  __builtin_amdgcn_s_barrier();
  asm volatile("" ::: "memory");

  for (int it = 0; it < 62; ++it) PV_BODY(it, "6", true, true);
  PV_BODY(62, "0", false, true);
  PV_BODY(63, "0", false, false);  // last body: no tail barrier needed

  // Epilogue: rd = 1/dacc — same C/D row mapping as acc, zero cross-lane.
  const int crow0 = bm + wm * 64 + 4 * half;
  const int ccol0 = bn + wn * 64 + ln31;
#pragma unroll
  for (int mt = 0; mt < 2; ++mt) {
#pragma unroll
    for (int r = 0; r < 16; ++r) {
      const int rl = crow0 + mt * 32 + (r & 3) + 8 * (r >> 2);
      const float rd = 1.0f / dacc[mt][r];
#pragma unroll
      for (int nt = 0; nt < 2; ++nt)
        Ob[(size_t)rl * 512 + ccol0 + nt * 32] = acc[mt][nt][r] * rd;
    }
  }
}

// ---------------------------------------------------------------------------
__global__ __launch_bounds__(256) void cvt_pair(const float* __restrict__ x,
                                                const float* __restrict__ y,
                                                u16* __restrict__ ox,
                                                u16* __restrict__ oy, int n4) {
  const int i = blockIdx.x * 256 + threadIdx.x;
  if (i >= n4) return;
  const float4 a = ((const float4*)x)[i];
  const float4 b = ((const float4*)y)[i];
  u16x4 oa, ob;
  oa[0] = f2bf(a.x); oa[1] = f2bf(a.y); oa[2] = f2bf(a.z); oa[3] = f2bf(a.w);
  ob[0] = f2bf(b.x); ob[1] = f2bf(b.y); ob[2] = f2bf(b.z); ob[3] = f2bf(b.w);
  ((u16x4*)ox)[i] = oa;
  ((u16x4*)oy)[i] = ob;
}

// ---------------------------------------------------------------------------
// 3 weight transposes in one launch (grid z selects the matrix).
__global__ __launch_bounds__(256) void wtrans_k3(
    const float* __restrict__ Wq, const float* __restrict__ Wk,
    const float* __restrict__ Wv, u16* __restrict__ WqT,
    u16* __restrict__ WkT, u16* __restrict__ WvT) {
  const int z = blockIdx.z;
  const float* W = z == 0 ? Wq : (z == 1 ? Wk : Wv);
  u16* WT = z == 0 ? WqT : (z == 1 ? WkT : WvT);
  const int tr = blockIdx.y * 64;
  const int tc = blockIdx.x * 64;
  __shared__ float T[64][65];
  const int t = threadIdx.x;
  const int r0 = t >> 4;
  const int c0 = (t & 15) * 4;
#pragma unroll
  for (int rr = 0; rr < 4; ++rr) {
    const int row = rr * 16 + r0;
    const float4 w = *(const float4*)&W[(size_t)(tr + row) * 512 + tc + c0];
    T[row][c0 + 0] = w.x; T[row][c0 + 1] = w.y;
    T[row][c0 + 2] = w.z; T[row][c0 + 3] = w.w;
  }
  __syncthreads();
#pragma unroll
  for (int rr = 0; rr < 4; ++rr) {
    const int orow = rr * 16 + r0;
    u16x4 o;
#pragma unroll
    for (int j = 0; j < 4; ++j) o[j] = f2bf(T[c0 + j][orow]);
    *(u16x4*)&WT[(size_t)(tc + orow) * 512 + tr + c0] = o;
  }
}

// ---------------------------------------------------------------------------
extern "C" void kernel_launch(void* const* d_in, const int* in_sizes, int n_in,
                              void* d_out, int out_size, void* d_ws,
                              size_t ws_size, hipStream_t stream) {
  const float* rgb = (const float*)d_in[0];
  const float* dep = (const float*)d_in[1];
  const float* Wq = (const float*)d_in[2];
  const float* bq = (const float*)d_in[3];
  const float* Wk = (const float*)d_in[4];
  const float* bk = (const float*)d_in[5];
  const float* Wv = (const float*)d_in[6];
  const float* bv = (const float*)d_in[7];
  float* out = (float*)d_out;

  const int B = 4, N = 4096, M = 4096, C = 512;
  const size_t nBNC = (size_t)B * N * C;
  const float scale = 0.044194173824159216f;  // 512^-0.5

  char* ws = (char*)d_ws;
  size_t off = 0;
  auto carve = [&](size_t bytes) -> void* {
    void* p = ws + off;
    off += (bytes + 255) & ~(size_t)255;
    return p;
  };
  u16* rgb_bf = (u16*)carve(nBNC * 2);
  u16* dep_bf = (u16*)carve(nBNC * 2);
  u16* WqT = (u16*)carve((size_t)C * C * 2);
  u16* WkT = (u16*)carve((size_t)C * C * 2);
  u16* WvT = (u16*)carve((size_t)C * C * 2);
  u16* Qb = (u16*)carve(nBNC * 2);
  u16* Kb = (u16*)carve(nBNC * 2);
  u16* Vt = (u16*)carve(nBNC * 2);
  u16* Sb = (u16*)carve((size_t)B * N * M * 2);  // 134 MB expS

  const long long strQ = (long long)N * C;  // 2,097,152
  const long long strS = (long long)N * M;  // 16,777,216
  const long long strV = (long long)C * M;  // 2,097,152

  // 0) conversions
  cvt_pair<<<8192, 256, 0, stream>>>(rgb, dep, rgb_bf, dep_bf, (int)(nBNC / 4));
  wtrans_k3<<<dim3(8, 8, 3), 256, 0, stream>>>(Wq, Wk, Wv, WqT, WkT, WvT);

  // 1) projections
  gemm32<128, 128, 1, 0, 4><<<dim3(4, 128, 1), 256, 0, stream>>>(
      rgb_bf, WqT, bq, Qb, 16384, 512, 512, 0, 0, 0, 1.f);
  gemm32<128, 128, 1, 0, 4><<<dim3(4, 128, 1), 256, 0, stream>>>(
      dep_bf, WkT, bk, Kb, 16384, 512, 512, 0, 0, 0, 1.f);
  gemm32<128, 128, 2, 0, 4><<<dim3(32, 4, 4), 256, 0, stream>>>(
      WvT, dep_bf, bv, Vt, 512, 4096, 512, 0, strQ, strV, 1.f);

  // 2) expS = exp(Q K^T * scale)  — 256^2 8-phase schedule
  gemm256_exp<<<dim3(16, 16, 4), 512, 0, stream>>>(Qb, Kb, Sb, strQ, strS,
                                                   scale);

  // 3) O = expS @ Vt^T / rowsum(expS)   (den via ones-MFMA, in-register)
  pv_gemm<<<dim3(2, 32, 4), 512, 0, stream>>>(Sb, Vt, out);
}

// Round 14
// 357.476 us; speedup vs baseline: 1.0834x; 1.0218x over previous
//
#include <hip/hip_runtime.h>
#include <hip/hip_bf16.h>
#include <stdint.h>

// CrossAttention (B=4, N=M=4096, C=512), fp32 in/out, bf16 MFMA internally.
// Round 12 (resubmit; infra failure, kernel never ran): pv_gemm body
// UNPINNED — R11 measured conflicts 8.39M->0 (theory confirmed) but pv only
// 137->122us: per-body model shows the explicit lgkmcnt(0)+sched_barrier(0)
// before the MFMAs serialized the LDS phase (1542cyc) against the MFMA
// phase (1536cyc) in 8-wave lockstep. Fix:
// (1) interleave per-ks ds_reads with MFMAs, compiler-scheduled counted
//     waits (m97-style); WAR closed by ONE lgkmcnt(0) AFTER the MFMAs,
//     before the end barrier (loads cannot sink past the memory clobber).
// (2) dacc dedup: wave wn computes the ones-MFMA rowsum only for ks==wn
//     (wave-uniform branch) -> 24->18 MFMA/body; partials summed across
//     the 4 wn-waves in an LDS epilogue (stride-36 pad, overlaid on Bs).
//   Q    = rgb @ WqT^T (+bq)          [16384 x 512]        gemm32
//   K    = dep @ WkT^T (+bk)          [16384 x 512]        gemm32
//   Vt   = WvT @ dep^T (+bv row)      per batch [512x4096] gemm32
//   expS = exp(Q K^T / sqrt(C))       per batch [4096^2]   gemm256_exp
//   O    = (expS @ Vt^T) / rowsum     per batch [4096x512] pv_gemm (v4)

typedef unsigned short u16;
typedef __attribute__((ext_vector_type(8))) short bf16x8;
typedef __attribute__((ext_vector_type(16))) float f32x16;
typedef __attribute__((ext_vector_type(4))) unsigned short u16x4;

#define GLD_LDS16(g, l)                                                        \
  __builtin_amdgcn_global_load_lds(                                            \
      (const __attribute__((address_space(1))) unsigned int*)(g),              \
      (__attribute__((address_space(3))) unsigned int*)(l), 16, 0, 0)

__device__ __forceinline__ u16 f2bf(float f) {  // RNE f32 -> bf16
  unsigned x = __float_as_uint(f);
  return (u16)((x + 0x7fffu + ((x >> 16) & 1u)) >> 16);
}
__device__ __forceinline__ float bf2f(short s) {
  return __uint_as_float((unsigned)(unsigned short)s << 16);
}

// ---------------------------------------------------------------------------
// GEMM: C[M,N] = A[M,K]*B[N,K]^T, bf16 in, fp32 acc, 32x32x16 MFMA.
// 256 thr / 4 waves (2x2), TM x TN tile, BK=32, double-buffered LDS, one
// barrier per iter. XOR bank swizzle on 16-B k-chunks (R3: 0 conflicts).
// OUT_MODE: 0 = bf16, 1 = fp32. BIAS_MODE: 0 none, 1 bias[col], 2 bias[row].
// ---------------------------------------------------------------------------
template <int TM, int TN, int BIAS_MODE, int OUT_MODE, int MINW>
__global__ __launch_bounds__(256, MINW) void gemm32(
    const u16* __restrict__ A, const u16* __restrict__ Bm,
    const float* __restrict__ bias, void* __restrict__ Cv, int M, int N, int K,
    long long sAb, long long sBb, long long sCb, float scale) {
  constexpr int WROWS = TM / 2;
  constexpr int WCOLS = TN / 2;
  constexpr int MSUB = WROWS / 32;
  constexpr int NSUB = WCOLS / 32;
  constexpr int CA = TM / 64;  // A 16-row chunks per wave
  constexpr int CB = TN / 64;  // B 16-row chunks per wave

  const int bz = blockIdx.z;
  A += (size_t)bz * sAb;
  Bm += (size_t)bz * sBb;

  const int bm = blockIdx.y * TM;
  const int bn = blockIdx.x * TN;

  __shared__ u16 As[2][TM * 32];
  __shared__ u16 Bs[2][TN * 32];

  const int tid = threadIdx.x;
  const int wave = tid >> 6;
  const int lane = tid & 63;
  const int ln31 = lane & 31;
  const int half = lane >> 5;
  const int wr = wave >> 1;
  const int wc = wave & 1;

  const int rowA = lane >> 2;
  const int swz = ((lane & 3) ^ ((rowA + (rowA >> 2)) & 3)) * 8;
  const int gl = (ln31 + (ln31 >> 2)) & 3;

  f32x16 acc[MSUB][NSUB] = {};

  auto stage = [&](int buf, int k0) {
#pragma unroll
    for (int r = 0; r < CA; ++r) {
      const int ch = wave * CA + r;
      GLD_LDS16(A + (size_t)(bm + ch * 16 + rowA) * K + k0 + swz,
                As[buf] + ch * 16 * 32);
    }
#pragma unroll
    for (int r = 0; r < CB; ++r) {
      const int ch = wave * CB + r;
      GLD_LDS16(Bm + (size_t)(bn + ch * 16 + rowA) * K + k0 + swz,
                Bs[buf] + ch * 16 * 32);
    }
  };

  const int niter = K >> 5;
  stage(0, 0);
  for (int it = 0; it < niter; ++it) {
    __syncthreads();  // publishes buf it&1 (vmcnt drained here)
    if (it + 1 < niter) stage((it + 1) & 1, (it + 1) * 32);
    const int buf = it & 1;
#pragma unroll
    for (int kc = 0; kc < 2; ++kc) {
      const int p = ((kc * 2 + half) ^ gl) * 8;
      bf16x8 af[MSUB], bfv[NSUB];
#pragma unroll
      for (int mt = 0; mt < MSUB; ++mt)
        af[mt] =
            *(const bf16x8*)&As[buf][(wr * WROWS + mt * 32 + ln31) * 32 + p];
#pragma unroll
      for (int nt = 0; nt < NSUB; ++nt)
        bfv[nt] =
            *(const bf16x8*)&Bs[buf][(wc * WCOLS + nt * 32 + ln31) * 32 + p];
#pragma unroll
      for (int mt = 0; mt < MSUB; ++mt)
#pragma unroll
        for (int nt = 0; nt < NSUB; ++nt)
          acc[mt][nt] = __builtin_amdgcn_mfma_f32_32x32x16_bf16(
              af[mt], bfv[nt], acc[mt][nt], 0, 0, 0);
    }
  }

  // Epilogue. 32x32 C/D layout: col = lane&31, row = (r&3)+8*(r>>2)+4*half.
  const int crow0 = bm + wr * WROWS + 4 * half;
  const int ccol0 = bn + wc * WCOLS + ln31;
#pragma unroll
  for (int mt = 0; mt < MSUB; ++mt) {
#pragma unroll
    for (int nt = 0; nt < NSUB; ++nt) {
      const int col = ccol0 + nt * 32;
#pragma unroll
      for (int r = 0; r < 16; ++r) {
        const int row = crow0 + mt * 32 + (r & 3) + 8 * (r >> 2);
        float v = acc[mt][nt][r];
        if constexpr (BIAS_MODE == 1) v += bias[col];
        if constexpr (BIAS_MODE == 2) v += bias[row];
        const size_t idx = (size_t)bz * (size_t)sCb + (size_t)row * N + col;
        if constexpr (OUT_MODE == 0)
          ((u16*)Cv)[idx] = f2bf(v);
        else if constexpr (OUT_MODE == 1)
          ((float*)Cv)[idx] = v;
        else
          ((u16*)Cv)[idx] = f2bf(__expf(v * scale));
      }
    }
  }
}

// ---------------------------------------------------------------------------
// gemm256_exp: S[4096,4096] = exp(scale * Q[4096,512] K[4096,512]^T) in bf16.
// 256x256 tile, BK=64, 512 thr / 8 waves (2M x 4N), per-wave 128x64 output.
// 4 quadrant-phases per K-tile; counted vmcnt 4/5/6/3 (never 0 mid-loop).
// Verified passing (incl. replay tripwire) R7-R11. Unchanged.
// ---------------------------------------------------------------------------
#define XA_STGA(buf, j, k0)                                                    \
  GLD_LDS16(Ag + (size_t)((j) * 32 + (wv & 3) * 8 + (wv >> 2) * 128 + rlane) * \
                    512 +                                                      \
                (k0) + swz8,                                                   \
            &As[buf][((j) * 32 + (wv & 3) * 8 + (wv >> 2) * 128) * 64])
#define XA_STGB(buf, j, k0)                                                    \
  GLD_LDS16(Bg + (size_t)((j) * 64 + wv * 8 + rlane) * 512 + (k0) + swz8,      \
            &Bs[buf][((j) * 64 + wv * 8) * 64])

#define XA_PHASE(F, NV, PFS)                                                   \
  {                                                                            \
    bf16x8 af[4];                                                              \
    {                                                                          \
      const int arow = (wm * 128 + (F) * 32 + ln31) * 64;                      \
      _Pragma("unroll") for (int k = 0; k < 4; ++k) af[k] =                    \
          *(const bf16x8*)&As[p][arow + (((2 * k + half) ^ s7) << 3)];         \
    }                                                                          \
    if ((F) == 0) {                                                            \
      _Pragma("unroll") for (int n = 0; n < 2; ++n) {                          \
        const int brow = (wn * 64 + n * 32 + ln31) * 64;                       \
        _Pragma("unroll") for (int k = 0; k < 4; ++k) bfr[n][k] =              \
            *(const bf16x8*)&Bs[p][brow + (((2 * k + half) ^ s7) << 3)];       \
      }                                                                        \
    }                                                                          \
    PFS;                                                                       \
    __builtin_amdgcn_s_barrier();                                              \
    asm volatile("s_waitcnt lgkmcnt(0)" ::: "memory");                         \
    __builtin_amdgcn_sched_barrier(0);                                         \
    __builtin_amdgcn_s_setprio(1);                                             \
    _Pragma("unroll") for (int k = 0; k < 4; ++k) {                            \
      acc[F][0] = __builtin_amdgcn_mfma_f32_32x32x16_bf16(af[k], bfr[0][k],    \
                                                          acc[F][0], 0, 0, 0); \
      acc[F][1] = __builtin_amdgcn_mfma_f32_32x32x16_bf16(af[k], bfr[1][k],    \
                                                          acc[F][1], 0, 0, 0); \
    }                                                                          \
    __builtin_amdgcn_s_setprio(0);                                             \
    asm volatile("s_waitcnt vmcnt(" NV ")" ::: "memory");                      \
    __builtin_amdgcn_s_barrier();                                              \
    asm volatile("" ::: "memory");                                             \
  }

__global__ __launch_bounds__(512, 2) void gemm256_exp(
    const u16* __restrict__ Qm, const u16* __restrict__ Km,
    u16* __restrict__ Sout, long long sAb, long long sSb, float scale) {
  const int bz = blockIdx.z;
  const int bm = blockIdx.y * 256;
  const int bn = blockIdx.x * 256;
  const u16* Ag = Qm + (size_t)bz * (size_t)sAb + (size_t)bm * 512;
  const u16* Bg = Km + (size_t)bz * (size_t)sAb + (size_t)bn * 512;

  __shared__ u16 As[2][256 * 64];  // 64 KB
  __shared__ u16 Bs[2][256 * 64];  // 64 KB

  const int tid = threadIdx.x;
  const int wv = tid >> 6;    // wave 0..7
  const int lane = tid & 63;
  const int ln31 = lane & 31;
  const int half = lane >> 5;
  const int wm = wv >> 2;     // 0..1: 128-row half
  const int wn = wv & 3;      // 0..3: 64-col group
  const int rlane = lane >> 3;                 // staged row within 8-row chunk
  const int swz8 = ((lane & 7) ^ rlane) << 3;  // pre-swizzled global k-offset
  const int s7 = ln31 & 7;                     // ds_read swizzle key

  f32x16 acc[4][2] = {};
  bf16x8 bfr[2][4];

  // prologue: stage tile 0 into buf 0 (issue order B0..B3, A0..A3)
#pragma unroll
  for (int j = 0; j < 4; ++j) XA_STGB(0, j, 0);
#pragma unroll
  for (int j = 0; j < 4; ++j) XA_STGA(0, j, 0);
  asm volatile("s_waitcnt vmcnt(3)" ::: "memory");  // B0-3 + A0 landed
  __builtin_amdgcn_s_barrier();
  asm volatile("" ::: "memory");

  for (int t = 0; t < 7; ++t) {  // K = 512 -> 8 tiles of 64
    const int p = t & 1;
    const int q = p ^ 1;
    const int kn = (t + 1) << 6;
    XA_PHASE(0, "4", { XA_STGB(q, 0, kn); XA_STGB(q, 1, kn); });
    XA_PHASE(1, "5", { XA_STGB(q, 2, kn); XA_STGB(q, 3, kn); });
    XA_PHASE(2, "6", { XA_STGA(q, 0, kn); XA_STGA(q, 1, kn); });
    XA_PHASE(3, "3", { XA_STGA(q, 2, kn); XA_STGA(q, 3, kn); });
  }
  {  // last tile: no prefetch, drain progressively
    const int p = 1;
    XA_PHASE(0, "2", {});
    XA_PHASE(1, "1", {});
    XA_PHASE(2, "0", {});
    XA_PHASE(3, "0", {});
  }

  // epilogue: exp + bf16 store. 32x32 layout: col=lane&31, row=(r&3)+8*(r>>2)+4*half.
  const size_t ob = (size_t)bz * (size_t)sSb;
  const int c0 = bn + wn * 64 + ln31;
  const int r0 = bm + wm * 128 + 4 * half;
#pragma unroll
  for (int m = 0; m < 4; ++m) {
#pragma unroll
    for (int n = 0; n < 2; ++n) {
      const int col = c0 + n * 32;
#pragma unroll
      for (int r = 0; r < 16; ++r) {
        const int row = r0 + m * 32 + (r & 3) + 8 * (r >> 2);
        Sout[ob + (size_t)row * 4096 + col] = f2bf(__expf(acc[m][n][r] * scale));
      }
    }
  }
}

// ---------------------------------------------------------------------------
// PV v4: O[4096 x 512] = (expS @ Vt^T) / rowsum, per batch.
// TM=128 x TN=256, BK=64, 512 thr / 8 waves (2M x 4N; per wave 64x64 out).
// Body (Round 12): {stage(t+2); interleaved per-ks {4 ds_read; 4-6 MFMA},
// compiler-scheduled counted waits; lgkmcnt(0) [WAR]; vmcnt(6); barrier}.
// No pre-MFMA lgkmcnt(0)/sched_barrier pin (R11's serializer). dacc rowsum
// computed only where ks==wn (wave-uniform branch) -> 18 MFMA/body; partials
// summed across the 4 wn-waves in an LDS epilogue (stride-36 f32 on Bs[0],
// which body 63 read and drained before the epilogue barrier).
// WAR: every wave's ds_reads of buf drain at its lgkmcnt(0), which precedes
//   the end barrier, which precedes any restage of that buf (2 bodies on).
// RAW: vmcnt(6) at body t leaves only stage(t+2) in flight -> tile t+1
//   resident before the barrier releases body t+1 reads. Tail 62:"0",63:none.
// Two-plane LDS layout + R2 swizzle (R11-verified: 0 bank conflicts).
// ---------------------------------------------------------------------------
#define PV_READ_KS(KS, BUF)                                                    \
  {                                                                            \
    constexpr int pl_ = (KS) >> 1;                                             \
    constexpr int kc_ = (KS) & 1;                                              \
    const int p = ((kc_ * 2 + half) ^ gl) * 8;                                 \
    af[KS][0] =                                                                \
        *(const bf16x8*)&As[BUF][(pl_ * 128 + wm * 64 + ln31) * 32 + p];       \
    af[KS][1] =                                                                \
        *(const bf16x8*)&As[BUF][(pl_ * 128 + wm * 64 + 32 + ln31) * 32 + p];  \
    bfv[KS][0] =                                                               \
        *(const bf16x8*)&Bs[BUF][(pl_ * 256 + wn * 64 + ln31) * 32 + p];       \
    bfv[KS][1] =                                                               \
        *(const bf16x8*)&Bs[BUF][(pl_ * 256 + wn * 64 + 32 + ln31) * 32 + p];  \
  }

#define PV_MFMA_KS(KS)                                                         \
  {                                                                            \
    if (wn == (KS)) {                                                          \
      dacc[0] = __builtin_amdgcn_mfma_f32_32x32x16_bf16(af[KS][0], onesv,      \
                                                        dacc[0], 0, 0, 0);     \
      dacc[1] = __builtin_amdgcn_mfma_f32_32x32x16_bf16(af[KS][1], onesv,      \
                                                        dacc[1], 0, 0, 0);     \
    }                                                                          \
    _Pragma("unroll") for (int mt = 0; mt < 2; ++mt)                           \
        _Pragma("unroll") for (int nt = 0; nt < 2; ++nt) acc[mt][nt] =         \
        __builtin_amdgcn_mfma_f32_32x32x16_bf16(af[KS][mt], bfv[KS][nt],       \
                                                acc[mt][nt], 0, 0, 0);         \
  }

#define PV_BODY(IT, NV, DO_STAGE, DO_TAIL)                                     \
  {                                                                            \
    const int buf = (IT) % 3;                                                  \
    if (DO_STAGE) stage(((IT) + 2) % 3, ((IT) + 2) * 64);                      \
    bf16x8 af[4][2], bfv[4][2];                                                \
    __builtin_amdgcn_s_setprio(1);                                             \
    PV_READ_KS(0, buf)                                                         \
    PV_READ_KS(1, buf)                                                         \
    PV_MFMA_KS(0)                                                              \
    PV_READ_KS(2, buf)                                                         \
    PV_MFMA_KS(1)                                                              \
    PV_READ_KS(3, buf)                                                         \
    PV_MFMA_KS(2)                                                              \
    PV_MFMA_KS(3)                                                              \
    __builtin_amdgcn_s_setprio(0);                                             \
    asm volatile("s_waitcnt lgkmcnt(0)" ::: "memory"); /* WAR drain */         \
    if (DO_TAIL) {                                                             \
      asm volatile("s_waitcnt vmcnt(" NV ")" ::: "memory");                    \
      __builtin_amdgcn_s_barrier();                                            \
      asm volatile("" ::: "memory");                                           \
    }                                                                          \
  }

__global__ __launch_bounds__(512, 2) void pv_gemm(
    const u16* __restrict__ P, const u16* __restrict__ Vt,
    float* __restrict__ O) {
  const int bz = blockIdx.z;
  const u16* A = P + (size_t)bz * (4096ull * 4096ull);
  const u16* B = Vt + (size_t)bz * (512ull * 4096ull);
  float* Ob = O + (size_t)bz * (4096ull * 512ull);

  const int bm = blockIdx.y * 128;  // q-row slab
  const int bn = blockIdx.x * 256;  // d half

  // two-plane layout: [buf][plane*ROWS + row][32 u16]
  __shared__ u16 As[3][2 * 128 * 32];  // 3 x 16 KB
  __shared__ u16 Bs[3][2 * 256 * 32];  // 3 x 32 KB  (144 KB total, 1 blk/CU)

  const int tid = threadIdx.x;
  const int wv = tid >> 6;  // wave 0..7
  const int lane = tid & 63;
  const int ln31 = lane & 31;
  const int half = lane >> 5;
  const int wm = wv >> 2;  // 0..1: 64-row half
  const int wn = wv & 3;   // 0..3: 64-col group

  // R2-verified zero-conflict swizzle (64-B rows, 4 chunks of 16 B):
  const int rowA = lane >> 2;  // staged row within 16-row group
  const int swz = ((lane & 3) ^ ((rowA + (rowA >> 2)) & 3)) * 8;
  const int gl = (ln31 + (ln31 >> 2)) & 3;

  f32x16 acc[2][2] = {};
  f32x16 dacc[2] = {};
  bf16x8 onesv;
#pragma unroll
  for (int j = 0; j < 8; ++j) onesv[j] = (short)0x3F80;  // bf16 1.0

  auto stage = [&](int buf, int k0) {
    // A: 16 gld (2/wave): id -> plane (id>>3), 16-row group (id&7).
#pragma unroll
    for (int r = 0; r < 2; ++r) {
      const int id = wv * 2 + r;
      const int pl = id >> 3, rg = id & 7;
      GLD_LDS16(A + (size_t)(bm + rg * 16 + rowA) * 4096 + k0 + pl * 32 + swz,
                As[buf] + (pl * 128 + rg * 16) * 32);
    }
    // B: 32 gld (4/wave): id -> plane (id>>4), 16-row group (id&15).
#pragma unroll
    for (int r = 0; r < 4; ++r) {
      const int id = wv * 4 + r;
      const int pl = id >> 4, rg = id & 15;
      GLD_LDS16(B + (size_t)(bn + rg * 16 + rowA) * 4096 + k0 + pl * 32 + swz,
                Bs[buf] + (pl * 256 + rg * 16) * 32);
    }
  };

  // prologue: stage tiles 0,1 (12 loads in flight); wait tile 0; publish.
  stage(0, 0);
  stage(1, 64);
  asm volatile("s_waitcnt vmcnt(6)" ::: "memory");
  __builtin_amdgcn_s_barrier();
  asm volatile("" ::: "memory");

  for (int it = 0; it < 62; ++it) PV_BODY(it, "6", true, true);
  PV_BODY(62, "0", false, true);
  PV_BODY(63, "0", false, false);  // lgkmcnt(0) still executed above

  // --- dacc combine across the 4 wn-waves (each holds 1 of 4 ks-slices) ---
  __builtin_amdgcn_s_barrier();  // all waves' body-63 reads drained
  asm volatile("" ::: "memory");
  float* dsum = (float*)&Bs[0][0];  // 8*64*36*4 = 73.7 KB <= 96 KB
  {
    const int base = (wv * 64 + lane) * 36;
#pragma unroll
    for (int mt = 0; mt < 2; ++mt)
#pragma unroll
      for (int r = 0; r < 16; ++r) dsum[base + mt * 16 + r] = dacc[mt][r];
  }
  __syncthreads();
  float den[2][16];
#pragma unroll
  for (int mt = 0; mt < 2; ++mt)
#pragma unroll
    for (int r = 0; r < 16; ++r) {
      float s = 0.f;
#pragma unroll
      for (int w = 0; w < 4; ++w)
        s += dsum[((wm * 4 + w) * 64 + lane) * 36 + mt * 16 + r];
      den[mt][r] = s;
    }

  // Epilogue: same C/D row mapping as acc, zero cross-lane.
  const int crow0 = bm + wm * 64 + 4 * half;
  const int ccol0 = bn + wn * 64 + ln31;
#pragma unroll
  for (int mt = 0; mt < 2; ++mt) {
#pragma unroll
    for (int r = 0; r < 16; ++r) {
      const int rl = crow0 + mt * 32 + (r & 3) + 8 * (r >> 2);
      const float rd = 1.0f / den[mt][r];
#pragma unroll
      for (int nt = 0; nt < 2; ++nt)
        Ob[(size_t)rl * 512 + ccol0 + nt * 32] = acc[mt][nt][r] * rd;
    }
  }
}

// ---------------------------------------------------------------------------
__global__ __launch_bounds__(256) void cvt_pair(const float* __restrict__ x,
                                                const float* __restrict__ y,
                                                u16* __restrict__ ox,
                                                u16* __restrict__ oy, int n4) {
  const int i = blockIdx.x * 256 + threadIdx.x;
  if (i >= n4) return;
  const float4 a = ((const float4*)x)[i];
  const float4 b = ((const float4*)y)[i];
  u16x4 oa, ob;
  oa[0] = f2bf(a.x); oa[1] = f2bf(a.y); oa[2] = f2bf(a.z); oa[3] = f2bf(a.w);
  ob[0] = f2bf(b.x); ob[1] = f2bf(b.y); ob[2] = f2bf(b.z); ob[3] = f2bf(b.w);
  ((u16x4*)ox)[i] = oa;
  ((u16x4*)oy)[i] = ob;
}

// ---------------------------------------------------------------------------
// 3 weight transposes in one launch (grid z selects the matrix).
__global__ __launch_bounds__(256) void wtrans_k3(
    const float* __restrict__ Wq, const float* __restrict__ Wk,
    const float* __restrict__ Wv, u16* __restrict__ WqT,
    u16* __restrict__ WkT, u16* __restrict__ WvT) {
  const int z = blockIdx.z;
  const float* W = z == 0 ? Wq : (z == 1 ? Wk : Wv);
  u16* WT = z == 0 ? WqT : (z == 1 ? WkT : WvT);
  const int tr = blockIdx.y * 64;
  const int tc = blockIdx.x * 64;
  __shared__ float T[64][65];
  const int t = threadIdx.x;
  const int r0 = t >> 4;
  const int c0 = (t & 15) * 4;
#pragma unroll
  for (int rr = 0; rr < 4; ++rr) {
    const int row = rr * 16 + r0;
    const float4 w = *(const float4*)&W[(size_t)(tr + row) * 512 + tc + c0];
    T[row][c0 + 0] = w.x; T[row][c0 + 1] = w.y;
    T[row][c0 + 2] = w.z; T[row][c0 + 3] = w.w;
  }
  __syncthreads();
#pragma unroll
  for (int rr = 0; rr < 4; ++rr) {
    const int orow = rr * 16 + r0;
    u16x4 o;
#pragma unroll
    for (int j = 0; j < 4; ++j) o[j] = f2bf(T[c0 + j][orow]);
    *(u16x4*)&WT[(size_t)(tc + orow) * 512 + tr + c0] = o;
  }
}

// ---------------------------------------------------------------------------
extern "C" void kernel_launch(void* const* d_in, const int* in_sizes, int n_in,
                              void* d_out, int out_size, void* d_ws,
                              size_t ws_size, hipStream_t stream) {
  const float* rgb = (const float*)d_in[0];
  const float* dep = (const float*)d_in[1];
  const float* Wq = (const float*)d_in[2];
  const float* bq = (const float*)d_in[3];
  const float* Wk = (const float*)d_in[4];
  const float* bk = (const float*)d_in[5];
  const float* Wv = (const float*)d_in[6];
  const float* bv = (const float*)d_in[7];
  float* out = (float*)d_out;

  const int B = 4, N = 4096, M = 4096, C = 512;
  const size_t nBNC = (size_t)B * N * C;
  const float scale = 0.044194173824159216f;  // 512^-0.5

  char* ws = (char*)d_ws;
  size_t off = 0;
  auto carve = [&](size_t bytes) -> void* {
    void* p = ws + off;
    off += (bytes + 255) & ~(size_t)255;
    return p;
  };
  u16* rgb_bf = (u16*)carve(nBNC * 2);
  u16* dep_bf = (u16*)carve(nBNC * 2);
  u16* WqT = (u16*)carve((size_t)C * C * 2);
  u16* WkT = (u16*)carve((size_t)C * C * 2);
  u16* WvT = (u16*)carve((size_t)C * C * 2);
  u16* Qb = (u16*)carve(nBNC * 2);
  u16* Kb = (u16*)carve(nBNC * 2);
  u16* Vt = (u16*)carve(nBNC * 2);
  u16* Sb = (u16*)carve((size_t)B * N * M * 2);  // 134 MB expS

  const long long strQ = (long long)N * C;  // 2,097,152
  const long long strS = (long long)N * M;  // 16,777,216
  const long long strV = (long long)C * M;  // 2,097,152

  // 0) conversions
  cvt_pair<<<8192, 256, 0, stream>>>(rgb, dep, rgb_bf, dep_bf, (int)(nBNC / 4));
  wtrans_k3<<<dim3(8, 8, 3), 256, 0, stream>>>(Wq, Wk, Wv, WqT, WkT, WvT);

  // 1) projections
  gemm32<128, 128, 1, 0, 4><<<dim3(4, 128, 1), 256, 0, stream>>>(
      rgb_bf, WqT, bq, Qb, 16384, 512, 512, 0, 0, 0, 1.f);
  gemm32<128, 128, 1, 0, 4><<<dim3(4, 128, 1), 256, 0, stream>>>(
      dep_bf, WkT, bk, Kb, 16384, 512, 512, 0, 0, 0, 1.f);
  gemm32<128, 128, 2, 0, 4><<<dim3(32, 4, 4), 256, 0, stream>>>(
      WvT, dep_bf, bv, Vt, 512, 4096, 512, 0, strQ, strV, 1.f);

  // 2) expS = exp(Q K^T * scale)  — 256^2 8-phase schedule
  gemm256_exp<<<dim3(16, 16, 4), 512, 0, stream>>>(Qb, Kb, Sb, strQ, strS,
                                                   scale);

  // 3) O = expS @ Vt^T / rowsum(expS)   (dacc dedup'd, LDS-combined)
  pv_gemm<<<dim3(2, 32, 4), 512, 0, stream>>>(Sb, Vt, out);
}